// Round 2
// baseline (2078.608 us; speedup 1.0000x reference)
//
#include <hip/hip_runtime.h>
#include <hip/hip_bf16.h>
#include <hip/hip_fp16.h>
#include <cstdint>
#include <cstddef>

// P=32, B=64, L=128, E=64, HB=128, HP=128, G=384, N=P*B=2048, PE=256, LH=128, NC=10

#define DINLINE __device__ __forceinline__

static DINLINE float sigmoidf_fast(float x) {
    return 1.0f / (1.0f + __expf(-x));
}
static DINLINE float tanhf_fast(float x) {
    float e2 = __expf(2.0f * x);
    return 1.0f - 2.0f / (e2 + 1.0f);
}

// ---------------------------------------------------------------------------
// K0a: byte tables: table[v][g] = b_ih[g] + sum_e emb[v][e]*w_ih[g][e]
// grid 512 (v=bx&255, dir=bx>>8), block 384
__global__ void k_tables(const float* __restrict__ emb,
                         const float* __restrict__ wihF, const float* __restrict__ bihF,
                         const float* __restrict__ wihB, const float* __restrict__ bihB,
                         float* __restrict__ tabF, float* __restrict__ tabB) {
    const int v = blockIdx.x & 255;
    const int dir = blockIdx.x >> 8;
    const float* wih = dir ? wihB : wihF;
    const float* bih = dir ? bihB : bihF;
    float* tab = dir ? tabB : tabF;
    __shared__ float er[64];
    if (threadIdx.x < 64) er[threadIdx.x] = emb[v * 64 + threadIdx.x];
    __syncthreads();
    const int g = threadIdx.x;  // 384 threads
    float acc = bih[g];
    #pragma unroll
    for (int e = 0; e < 64; ++e) acc = fmaf(wih[g * 64 + e], er[e], acc);
    tab[v * 384 + g] = acc;
}

// ---------------------------------------------------------------------------
// K0b: transposes (8 matrices). out[c*R + r] = in[r*C + c]
struct TransArgs {
    const float* src[8];
    float* dst[8];
    int R[8];
    int C[8];
};
__global__ void k_transpose(TransArgs a) {
    const int m = blockIdx.y;
    const float* __restrict__ s = a.src[m];
    float* __restrict__ d = a.dst[m];
    const int R = a.R[m], C = a.C[m];
    const int total = R * C;
    for (int idx = blockIdx.x * blockDim.x + threadIdx.x; idx < total;
         idx += gridDim.x * blockDim.x) {
        const int r = idx / C, c = idx - r * C;
        d[c * R + r] = s[idx];
    }
}

// ---------------------------------------------------------------------------
// K2: byte BiGRU recurrence. grid 256 (dir=bx&1, chunk=bx>>1: 16 rows each),
// block 256. h fp32 in LDS; wT=[128][384] streamed from L2; output stored fp16.
__global__ __launch_bounds__(256, 1) void k_byte_gru(
    const int* __restrict__ flow,
    const float* __restrict__ tabF, const float* __restrict__ tabB,
    const float* __restrict__ wTF, const float* __restrict__ wTB,
    const float* __restrict__ bhhF, const float* __restrict__ bhhB,
    __half* __restrict__ hF, __half* __restrict__ hB) {
    const int dir = blockIdx.x & 1;
    const int chunk = blockIdx.x >> 1;  // 0..127
    const int row0 = chunk * 16;
    const int tid = threadIdx.x;
    const int j = tid & 127;
    const int r0 = (tid >> 7) * 8;

    const float* __restrict__ tab = dir ? tabB : tabF;
    const float* __restrict__ wT = dir ? wTB : wTF;
    const float* __restrict__ bhh = dir ? bhhB : bhhF;
    __half* __restrict__ hout = dir ? hB : hF;

    __shared__ float h_lds[16][128];
    __shared__ int flow_lds[16][128];

    #pragma unroll
    for (int r = 0; r < 8; ++r) h_lds[r0 + r][j] = 0.0f;
    for (int i = tid; i < 16 * 128; i += 256) {
        flow_lds[i >> 7][i & 127] = flow[row0 * 128 + i];
    }
    const float bh0 = bhh[j], bh1 = bhh[j + 128], bh2 = bhh[j + 256];
    __syncthreads();

    for (int t = 0; t < 128; ++t) {
        const int tt = dir ? (127 - t) : t;
        float a0[8], a1[8], a2[8];
        #pragma unroll
        for (int r = 0; r < 8; ++r) { a0[r] = 0.f; a1[r] = 0.f; a2[r] = 0.f; }

        #pragma unroll 2
        for (int hh = 0; hh < 128; hh += 4) {
            float4 hv[8];
            #pragma unroll
            for (int r = 0; r < 8; ++r)
                hv[r] = *reinterpret_cast<const float4*>(&h_lds[r0 + r][hh]);
            #pragma unroll
            for (int u = 0; u < 4; ++u) {
                const float* wrow = wT + (hh + u) * 384 + j;
                const float w0 = wrow[0];
                const float w1 = wrow[128];
                const float w2 = wrow[256];
                #pragma unroll
                for (int r = 0; r < 8; ++r) {
                    const float hvv = (&hv[r].x)[u];
                    a0[r] = fmaf(w0, hvv, a0[r]);
                    a1[r] = fmaf(w1, hvv, a1[r]);
                    a2[r] = fmaf(w2, hvv, a2[r]);
                }
            }
        }
        __syncthreads();
        #pragma unroll
        for (int r = 0; r < 8; ++r) {
            const int row = r0 + r;
            const int n = row0 + row;
            const int byte = flow_lds[row][tt] & 255;  // defensive mask
            const float* tb = tab + byte * 384 + j;
            const float xr = tb[0], xz = tb[128], xn = tb[256];
            const float rg = sigmoidf_fast(xr + a0[r] + bh0);
            const float zg = sigmoidf_fast(xz + a1[r] + bh1);
            const float ng = tanhf_fast(xn + rg * (a2[r] + bh2));
            const float hold = h_lds[row][j];
            const float hnew = (1.f - zg) * ng + zg * hold;
            h_lds[row][j] = hnew;
            hout[((size_t)tt * 2048 + n) * 128 + j] = __float2half(hnew);
        }
        __syncthreads();
    }
}

// ---------------------------------------------------------------------------
// K3a: byte attention scores. score[pos] = w2 . tanh(W1 @ out[pos] + b1) + b2
// grid 2048 (128 positions each), block 256, 8x8 register tile, 8 d-chunks of 32.
__global__ __launch_bounds__(256, 2) void k_scores(
    const __half* __restrict__ hF, const __half* __restrict__ hB,
    const float* __restrict__ w1T,  // [256][128]
    const float* __restrict__ b1, const float* __restrict__ w2,
    const float* __restrict__ b2, float* __restrict__ scores) {
    __shared__ float xs[128][33];
    __shared__ float wlds[32][128];
    const int tid = threadIdx.x;
    const int tk = tid & 15, tp = tid >> 4;
    const int k0 = tk * 8, p0 = tp * 8;
    const int pos0 = blockIdx.x * 128;

    float acc[8][8];
    #pragma unroll
    for (int q = 0; q < 8; ++q)
        #pragma unroll
        for (int p = 0; p < 8; ++p) acc[q][p] = 0.f;

    for (int dc = 0; dc < 8; ++dc) {
        __syncthreads();
        const __half* __restrict__ hsrc = (dc < 4) ? hF : hB;
        const int dbase = (dc & 3) * 32;
        const int dglob = (dc >> 2) * 128 + dbase;
        for (int i = tid; i < 128 * 32; i += 256) {
            const int pos = i >> 5, dl = i & 31;
            const int posg = pos0 + pos;
            const int l = posg >> 11, n = posg & 2047;
            xs[pos][dl] =
                __half2float(hsrc[((size_t)l * 2048 + n) * 128 + dbase + dl]);
        }
        for (int i = tid; i < 32 * 128; i += 256) {
            const int dd = i >> 7, k = i & 127;
            wlds[dd][k] = w1T[(dglob + dd) * 128 + k];
        }
        __syncthreads();
        for (int dd = 0; dd < 32; ++dd) {
            float xv[8], wv[8];
            #pragma unroll
            for (int p = 0; p < 8; ++p) xv[p] = xs[p0 + p][dd];
            #pragma unroll
            for (int q = 0; q < 8; ++q) wv[q] = wlds[dd][k0 + q];
            #pragma unroll
            for (int q = 0; q < 8; ++q)
                #pragma unroll
                for (int p = 0; p < 8; ++p)
                    acc[q][p] = fmaf(wv[q], xv[p], acc[q][p]);
        }
    }
    float b1v[8], w2v[8];
    #pragma unroll
    for (int q = 0; q < 8; ++q) { b1v[q] = b1[k0 + q]; w2v[q] = w2[k0 + q]; }
    const float b2v = b2[0];
    #pragma unroll
    for (int p = 0; p < 8; ++p) {
        float s = 0.f;
        #pragma unroll
        for (int q = 0; q < 8; ++q)
            s = fmaf(w2v[q], tanhf_fast(acc[q][p] + b1v[q]), s);
        s += __shfl_xor(s, 1);
        s += __shfl_xor(s, 2);
        s += __shfl_xor(s, 4);
        s += __shfl_xor(s, 8);
        if (tk == 0) scores[pos0 + p0 + p] = s + b2v;
    }
}

// ---------------------------------------------------------------------------
// K3a2: softmax over b (axis=2). grid 4096 = (l*32+p), block 64.
__global__ void k_attn_softmax(const float* __restrict__ scores,
                               float* __restrict__ attn) {
    const int lp = blockIdx.x;
    const float s = scores[lp * 64 + threadIdx.x];
    float m = s;
    for (int off = 32; off; off >>= 1) m = fmaxf(m, __shfl_xor(m, off));
    const float e = __expf(s - m);
    float sum = e;
    for (int off = 32; off; off >>= 1) sum += __shfl_xor(sum, off);
    attn[lp * 64 + threadIdx.x] = e / sum;
}

// ---------------------------------------------------------------------------
// K3b: packet_emb[p,b,d] = sum_l attn[l,p,b] * out[l,p,b,d]. grid 2048 (n), block 256.
__global__ __launch_bounds__(256) void k_packet_emb(
    const __half* __restrict__ hF, const __half* __restrict__ hB,
    const float* __restrict__ attn, float* __restrict__ pe) {
    const int n = blockIdx.x;
    const int tid = threadIdx.x;
    const __half* __restrict__ hsrc = (tid < 128) ? hF : hB;
    const int d = tid & 127;
    float acc = 0.f;
    for (int l = 0; l < 128; ++l) {
        const float w = attn[l * 2048 + n];
        acc = fmaf(w, __half2float(hsrc[((size_t)l * 2048 + n) * 128 + d]), acc);
    }
    pe[n * 256 + tid] = acc;
}

// ---------------------------------------------------------------------------
// K4pre: xg2[p,n,g] = b_ih[g] + sum_d pe[p,n,d]*w_ih[g,d]. grid (256,2), block 384.
__global__ __launch_bounds__(384) void k_pkt_xg(
    const float* __restrict__ pe, const float* __restrict__ wihTF,
    const float* __restrict__ bihF, const float* __restrict__ wihTB,
    const float* __restrict__ bihB, float* __restrict__ xgF,
    float* __restrict__ xgB) {
    const int dir = blockIdx.y;
    const float* __restrict__ wihT = dir ? wihTB : wihTF;
    const float* __restrict__ bih = dir ? bihB : bihF;
    float* __restrict__ xg = dir ? xgB : xgF;
    const int rbase = blockIdx.x * 8;
    __shared__ float xrow[8][256];
    for (int i = threadIdx.x; i < 8 * 256; i += 384)
        xrow[i >> 8][i & 255] = pe[rbase * 256 + i];
    __syncthreads();
    const int g = threadIdx.x;
    float acc[8];
    #pragma unroll
    for (int r = 0; r < 8; ++r) acc[r] = bih[g];
    for (int d = 0; d < 256; ++d) {
        const float w = wihT[d * 384 + g];
        #pragma unroll
        for (int r = 0; r < 8; ++r) acc[r] = fmaf(w, xrow[r][d], acc[r]);
    }
    #pragma unroll
    for (int r = 0; r < 8; ++r) xg[(rbase + r) * 384 + g] = acc[r];
}

// ---------------------------------------------------------------------------
// K4: packet BiGRU. grid 32 (dir=bx&1, chunk=bx>>1: 4 rows), block 256, 32 steps.
__global__ __launch_bounds__(256, 1) void k_pkt_gru(
    const float* __restrict__ xgF, const float* __restrict__ xgB,
    const float* __restrict__ wTF, const float* __restrict__ wTB,
    const float* __restrict__ bhhF, const float* __restrict__ bhhB,
    float* __restrict__ h2F, float* __restrict__ h2B) {
    const int dir = blockIdx.x & 1;
    const int chunk = blockIdx.x >> 1;  // 0..15
    const int row0 = chunk * 4;
    const int tid = threadIdx.x;
    const int j = tid & 127;
    const int r0 = (tid >> 7) * 2;
    const float* __restrict__ xg = dir ? xgB : xgF;
    const float* __restrict__ wT = dir ? wTB : wTF;
    const float* __restrict__ bhh = dir ? bhhB : bhhF;
    float* __restrict__ hout = dir ? h2B : h2F;

    __shared__ float h_lds[4][128];
    #pragma unroll
    for (int r = 0; r < 2; ++r) h_lds[r0 + r][j] = 0.f;
    const float bh0 = bhh[j], bh1 = bhh[j + 128], bh2 = bhh[j + 256];
    __syncthreads();

    for (int t = 0; t < 32; ++t) {
        const int tt = dir ? (31 - t) : t;
        float a0[2], a1[2], a2[2];
        a0[0] = a0[1] = a1[0] = a1[1] = a2[0] = a2[1] = 0.f;
        #pragma unroll 2
        for (int hh = 0; hh < 128; hh += 4) {
            float4 hv[2];
            #pragma unroll
            for (int r = 0; r < 2; ++r)
                hv[r] = *reinterpret_cast<const float4*>(&h_lds[r0 + r][hh]);
            #pragma unroll
            for (int u = 0; u < 4; ++u) {
                const float* wrow = wT + (hh + u) * 384 + j;
                const float w0 = wrow[0], w1 = wrow[128], w2 = wrow[256];
                #pragma unroll
                for (int r = 0; r < 2; ++r) {
                    const float hvv = (&hv[r].x)[u];
                    a0[r] = fmaf(w0, hvv, a0[r]);
                    a1[r] = fmaf(w1, hvv, a1[r]);
                    a2[r] = fmaf(w2, hvv, a2[r]);
                }
            }
        }
        __syncthreads();
        #pragma unroll
        for (int r = 0; r < 2; ++r) {
            const int row = r0 + r;
            const int n = row0 + row;
            const float* xp = xg + ((size_t)tt * 64 + n) * 384 + j;
            const float xr = xp[0], xz = xp[128], xn = xp[256];
            const float rg = sigmoidf_fast(xr + a0[r] + bh0);
            const float zg = sigmoidf_fast(xz + a1[r] + bh1);
            const float ng = tanhf_fast(xn + rg * (a2[r] + bh2));
            const float hold = h_lds[row][j];
            const float hnew = (1.f - zg) * ng + zg * hold;
            h_lds[row][j] = hnew;
            hout[((size_t)tt * 64 + n) * 128 + j] = hnew;
        }
        __syncthreads();
    }
}

// ---------------------------------------------------------------------------
// K5: packet attention + softmax(axis=b) + weighted sum over b + final FC.
// grid 32 (p), block 256.
__global__ __launch_bounds__(256) void k_final(
    const float* __restrict__ h2F, const float* __restrict__ h2B,
    const float* __restrict__ paw1T,  // [256][128]
    const float* __restrict__ pab1, const float* __restrict__ paw2,
    const float* __restrict__ pab2, const float* __restrict__ wf,
    const float* __restrict__ bfv, float* __restrict__ outp) {
    const int p = blockIdx.x;
    const int tid = threadIdx.x;
    __shared__ float sc[64];
    __shared__ float red[64];
    __shared__ float femb[256];
    __shared__ float x2[2][256];

    const int k = tid & 127;
    const int bh = tid >> 7;
    const float b1v = pab1[k];
    const float w2v = paw2[k];

    for (int bb = 0; bb < 32; ++bb) {
        for (int i = tid; i < 512; i += 256) {
            const int bi = i >> 8, dd = i & 255;
            const int n = p * 64 + bb * 2 + bi;
            x2[bi][dd] = (dd < 128) ? h2F[n * 128 + dd] : h2B[n * 128 + dd - 128];
        }
        __syncthreads();
        float acc = 0.f;
        #pragma unroll 4
        for (int d = 0; d < 256; ++d)
            acc = fmaf(paw1T[d * 128 + k], x2[bh][d], acc);
        float s = w2v * tanhf_fast(acc + b1v);
        s += __shfl_xor(s, 1);
        s += __shfl_xor(s, 2);
        s += __shfl_xor(s, 4);
        s += __shfl_xor(s, 8);
        s += __shfl_xor(s, 16);
        s += __shfl_xor(s, 32);
        if ((tid & 63) == 0) red[tid >> 6] = s;  // 4 wave partials
        __syncthreads();
        if (tid < 2) sc[bb * 2 + tid] = red[tid * 2] + red[tid * 2 + 1] + pab2[0];
        __syncthreads();
    }

    if (tid < 64) {
        const float s = sc[tid];
        float m = s;
        for (int off = 32; off; off >>= 1) m = fmaxf(m, __shfl_xor(m, off));
        const float e = __expf(s - m);
        float sum = e;
        for (int off = 32; off; off >>= 1) sum += __shfl_xor(sum, off);
        sc[tid] = e / sum;
    }
    __syncthreads();

    {
        const float* __restrict__ hsrc = (tid < 128) ? h2F : h2B;
        const int d = tid & 127;
        float acc = 0.f;
        for (int b = 0; b < 64; ++b)
            acc = fmaf(sc[b], hsrc[(p * 64 + b) * 128 + d], acc);
        femb[tid] = acc;
    }
    __syncthreads();

    const float fv = femb[tid];
    #pragma unroll
    for (int c = 0; c < 10; ++c) {
        float s = fv * wf[c * 256 + tid];
        s += __shfl_xor(s, 1);
        s += __shfl_xor(s, 2);
        s += __shfl_xor(s, 4);
        s += __shfl_xor(s, 8);
        s += __shfl_xor(s, 16);
        s += __shfl_xor(s, 32);
        if ((tid & 63) == 0) red[(c << 2) | (tid >> 6)] = s;
        __syncthreads();
        if (tid == 0)
            outp[p * 10 + c] = bfv[c] + red[c << 2] + red[(c << 2) | 1] +
                               red[(c << 2) | 2] + red[(c << 2) | 3];
        __syncthreads();
    }
}

// ---------------------------------------------------------------------------
extern "C" void kernel_launch(void* const* d_in, const int* in_sizes, int n_in,
                              void* d_out, int out_size, void* d_ws,
                              size_t ws_size, hipStream_t stream) {
    const int* flow = (const int*)d_in[0];
    const float* emb = (const float*)d_in[1];
    const float* byte_wih_f = (const float*)d_in[2];
    const float* byte_whh_f = (const float*)d_in[3];
    const float* byte_bih_f = (const float*)d_in[4];
    const float* byte_bhh_f = (const float*)d_in[5];
    const float* byte_wih_b = (const float*)d_in[6];
    const float* byte_whh_b = (const float*)d_in[7];
    const float* byte_bih_b = (const float*)d_in[8];
    const float* byte_bhh_b = (const float*)d_in[9];
    const float* pkt_wih_f = (const float*)d_in[10];
    const float* pkt_whh_f = (const float*)d_in[11];
    const float* pkt_bih_f = (const float*)d_in[12];
    const float* pkt_bhh_f = (const float*)d_in[13];
    const float* pkt_wih_b = (const float*)d_in[14];
    const float* pkt_whh_b = (const float*)d_in[15];
    const float* pkt_bih_b = (const float*)d_in[16];
    const float* pkt_bhh_b = (const float*)d_in[17];
    const float* ba_w1 = (const float*)d_in[18];
    const float* ba_b1 = (const float*)d_in[19];
    const float* ba_w2 = (const float*)d_in[20];
    const float* ba_b2 = (const float*)d_in[21];
    const float* pa_w1 = (const float*)d_in[22];
    const float* pa_b1 = (const float*)d_in[23];
    const float* pa_w2 = (const float*)d_in[24];
    const float* pa_b2 = (const float*)d_in[25];
    const float* wf = (const float*)d_in[26];
    const float* bf = (const float*)d_in[27];

    // ---- workspace layout (byte-based, with explicit size guard) ----
    char* base = (char*)d_ws;
    size_t off = 0;
    auto allocf = [&](size_t nf) -> float* {
        float* p = (float*)(base + off);
        off += nf * sizeof(float);
        return p;
    };
    auto alloch = [&](size_t nh) -> __half* {
        __half* p = (__half*)(base + off);
        off += nh * sizeof(__half);
        off = (off + 15) & ~(size_t)15;
        return p;
    };
    float* tabF = allocf(256 * 384);
    float* tabB = allocf(256 * 384);
    float* wTbF = allocf(128 * 384);
    float* wTbB = allocf(128 * 384);
    float* wTpF = allocf(128 * 384);
    float* wTpB = allocf(128 * 384);
    float* wihTpF = allocf(256 * 384);
    float* wihTpB = allocf(256 * 384);
    float* baw1T = allocf(256 * 128);
    float* paw1T = allocf(256 * 128);
    float* scores = allocf(262144);
    float* attn = allocf(262144);
    float* pe = allocf(2048 * 256);
    float* xgF = allocf(32 * 64 * 384);
    float* xgB = allocf(32 * 64 * 384);
    float* h2F = allocf(32 * 64 * 128);
    float* h2B = allocf(32 * 64 * 128);
    __half* hF = alloch((size_t)128 * 2048 * 128);
    __half* hB = alloch((size_t)128 * 2048 * 128);
    if (off > ws_size) return;  // diagnostic: leaves d_out poisoned
    (void)in_sizes; (void)n_in; (void)out_size;

    k_tables<<<512, 384, 0, stream>>>(emb, byte_wih_f, byte_bih_f, byte_wih_b,
                                      byte_bih_b, tabF, tabB);

    TransArgs ta;
    ta.src[0] = byte_whh_f; ta.dst[0] = wTbF;   ta.R[0] = 384; ta.C[0] = 128;
    ta.src[1] = byte_whh_b; ta.dst[1] = wTbB;   ta.R[1] = 384; ta.C[1] = 128;
    ta.src[2] = pkt_whh_f;  ta.dst[2] = wTpF;   ta.R[2] = 384; ta.C[2] = 128;
    ta.src[3] = pkt_whh_b;  ta.dst[3] = wTpB;   ta.R[3] = 384; ta.C[3] = 128;
    ta.src[4] = pkt_wih_f;  ta.dst[4] = wihTpF; ta.R[4] = 384; ta.C[4] = 256;
    ta.src[5] = pkt_wih_b;  ta.dst[5] = wihTpB; ta.R[5] = 384; ta.C[5] = 256;
    ta.src[6] = ba_w1;      ta.dst[6] = baw1T;  ta.R[6] = 128; ta.C[6] = 256;
    ta.src[7] = pa_w1;      ta.dst[7] = paw1T;  ta.R[7] = 128; ta.C[7] = 256;
    k_transpose<<<dim3(96, 8), 256, 0, stream>>>(ta);

    k_byte_gru<<<256, 256, 0, stream>>>(flow, tabF, tabB, wTbF, wTbB,
                                        byte_bhh_f, byte_bhh_b, hF, hB);

    k_scores<<<2048, 256, 0, stream>>>(hF, hB, baw1T, ba_b1, ba_w2, ba_b2,
                                       scores);
    k_attn_softmax<<<4096, 64, 0, stream>>>(scores, attn);
    k_packet_emb<<<2048, 256, 0, stream>>>(hF, hB, attn, pe);

    k_pkt_xg<<<dim3(256, 2), 384, 0, stream>>>(pe, wihTpF, pkt_bih_f, wihTpB,
                                               pkt_bih_b, xgF, xgB);
    k_pkt_gru<<<32, 256, 0, stream>>>(xgF, xgB, wTpF, wTpB, pkt_bhh_f,
                                      pkt_bhh_b, h2F, h2B);
    k_final<<<32, 256, 0, stream>>>(h2F, h2B, paw1T, pa_b1, pa_w2, pa_b2, wf,
                                    bf, (float*)d_out);
}

// Round 3
// 890.369 us; speedup vs baseline: 2.3345x; 2.3345x over previous
//
#include <hip/hip_runtime.h>
#include <hip/hip_bf16.h>
#include <hip/hip_fp16.h>
#include <cstdint>
#include <cstddef>

// P=32, B=64, L=128, E=64, HB=128, HP=128, G=384, N=P*B=2048, PE=256, LH=128, NC=10

#define DINLINE __device__ __forceinline__

typedef _Float16 f16;
typedef f16 f16x8 __attribute__((ext_vector_type(8)));
typedef float f32x4 __attribute__((ext_vector_type(4)));

static DINLINE float sigmoidf_fast(float x) {
    return 1.0f / (1.0f + __expf(-x));
}
static DINLINE float tanhf_fast(float x) {
    float e2 = __expf(2.0f * x);
    return 1.0f - 2.0f / (e2 + 1.0f);
}

// ---------------------------------------------------------------------------
// K0a: byte tables: table[v][g] = b_ih[g] + sum_e emb[v][e]*w_ih[g][e]
__global__ void k_tables(const float* __restrict__ emb,
                         const float* __restrict__ wihF, const float* __restrict__ bihF,
                         const float* __restrict__ wihB, const float* __restrict__ bihB,
                         float* __restrict__ tabF, float* __restrict__ tabB) {
    const int v = blockIdx.x & 255;
    const int dir = blockIdx.x >> 8;
    const float* wih = dir ? wihB : wihF;
    const float* bih = dir ? bihB : bihF;
    float* tab = dir ? tabB : tabF;
    __shared__ float er[64];
    if (threadIdx.x < 64) er[threadIdx.x] = emb[v * 64 + threadIdx.x];
    __syncthreads();
    const int g = threadIdx.x;  // 384 threads
    float acc = bih[g];
    #pragma unroll
    for (int e = 0; e < 64; ++e) acc = fmaf(wih[g * 64 + e], er[e], acc);
    tab[v * 384 + g] = acc;
}

// ---------------------------------------------------------------------------
// K0b: transposes (6 matrices). out[c*R + r] = in[r*C + c]
struct TransArgs {
    const float* src[6];
    float* dst[6];
    int R[6];
    int C[6];
};
__global__ void k_transpose(TransArgs a) {
    const int m = blockIdx.y;
    const float* __restrict__ s = a.src[m];
    float* __restrict__ d = a.dst[m];
    const int R = a.R[m], C = a.C[m];
    const int total = R * C;
    for (int idx = blockIdx.x * blockDim.x + threadIdx.x; idx < total;
         idx += gridDim.x * blockDim.x) {
        const int r = idx / C, c = idx - r * C;
        d[c * R + r] = s[idx];
    }
}

// ---------------------------------------------------------------------------
// K2: byte BiGRU recurrence via MFMA f16. grid 256 (dir=bx&1, chunk=bx>>1: 16
// rows), block 512 (8 waves; wave w owns h-cols [16w,16w+16) for all 3 gates).
// W_hh in VGPRs (fp16, from original [384][128] layout); h as fp16 in
// XOR-swizzled double-buffered LDS; fp32 h-state in registers.
__global__ __launch_bounds__(512, 1) void k_byte_gru(
    const int* __restrict__ flow,
    const float* __restrict__ tabF, const float* __restrict__ tabB,
    const float* __restrict__ whhF, const float* __restrict__ whhB,
    const float* __restrict__ bhhF, const float* __restrict__ bhhB,
    __half* __restrict__ hF, __half* __restrict__ hB) {
    const int dir = blockIdx.x & 1;
    const int chunk = blockIdx.x >> 1;  // 0..127
    const int row0 = chunk * 16;
    const int tid = threadIdx.x;
    const int wid = tid >> 6;
    const int lane = tid & 63;
    const int c = lane & 15;
    const int q = lane >> 4;
    const int j = wid * 16 + c;  // h-col this lane produces

    const float* __restrict__ tab = dir ? tabB : tabF;
    const float* __restrict__ whh = dir ? whhB : whhF;
    const float* __restrict__ bhh = dir ? bhhB : bhhF;
    __half* __restrict__ hout = dir ? hB : hF;

    __shared__ f16 hbuf[2][16 * 128];      // swizzled: idx = row*128 + (k ^ ((row&7)<<3))
    __shared__ int flow_lds[16][128];

    for (int i = tid; i < 16 * 128; i += 512)
        flow_lds[i >> 7][i & 127] = flow[row0 * 128 + i] & 255;
    for (int i = tid; i < 16 * 128; i += 512) hbuf[0][i] = (f16)0.f;

    // Preload B fragments: B[k][col] = whh[(g*128+j)][k], k consecutive.
    // frag lane layout: col = lane&15, k = (lane>>4)*8 + e + ks*32
    f16x8 Bf[3][4];
    #pragma unroll
    for (int g = 0; g < 3; ++g) {
        #pragma unroll
        for (int ks = 0; ks < 4; ++ks) {
            const float* src = whh + (size_t)(g * 128 + j) * 128 + ks * 32 + q * 8;
            f16x8 b;
            #pragma unroll
            for (int e = 0; e < 8; ++e) b[e] = (f16)src[e];
            Bf[g][ks] = b;
        }
    }
    const float bh0 = bhh[j], bh1 = bhh[j + 128], bh2 = bhh[j + 256];
    float hold[4];
    #pragma unroll
    for (int rr = 0; rr < 4; ++rr) hold[rr] = 0.f;
    __syncthreads();

    for (int t = 0; t < 128; ++t) {
        const int curb = t & 1, nxtb = curb ^ 1;
        const int tt = dir ? (127 - t) : t;

        // xg gathers for this step (issued early; consumed after MFMA)
        int byt[4];
        #pragma unroll
        for (int rr = 0; rr < 4; ++rr) byt[rr] = flow_lds[q * 4 + rr][tt];
        float xr[4], xz[4], xn[4];
        #pragma unroll
        for (int rr = 0; rr < 4; ++rr) {
            const float* tb = tab + byt[rr] * 384 + j;
            xr[rr] = tb[0];
            xz[rr] = tb[128];
            xn[rr] = tb[256];
        }

        // A fragments: lane row = c, k = ks*32 + q*8 + e  (swizzled LDS)
        f16x8 Af[4];
        #pragma unroll
        for (int ks = 0; ks < 4; ++ks) {
            const int kb = ks * 32 + q * 8;
            const int idx = c * 128 + (kb ^ ((c & 7) << 3));
            Af[ks] = *reinterpret_cast<const f16x8*>(&hbuf[curb][idx]);
        }

        f32x4 a0 = {0.f, 0.f, 0.f, 0.f};
        f32x4 a1 = {0.f, 0.f, 0.f, 0.f};
        f32x4 a2 = {0.f, 0.f, 0.f, 0.f};
        #pragma unroll
        for (int ks = 0; ks < 4; ++ks) {
            a0 = __builtin_amdgcn_mfma_f32_16x16x32_f16(Af[ks], Bf[0][ks], a0, 0, 0, 0);
            a1 = __builtin_amdgcn_mfma_f32_16x16x32_f16(Af[ks], Bf[1][ks], a1, 0, 0, 0);
            a2 = __builtin_amdgcn_mfma_f32_16x16x32_f16(Af[ks], Bf[2][ks], a2, 0, 0, 0);
        }

        // gates + state update; C layout: col=lane&15 (=j), row=q*4+rr
        #pragma unroll
        for (int rr = 0; rr < 4; ++rr) {
            const float rg = sigmoidf_fast(xr[rr] + a0[rr] + bh0);
            const float zg = sigmoidf_fast(xz[rr] + a1[rr] + bh1);
            const float ng = tanhf_fast(xn[rr] + rg * (a2[rr] + bh2));
            const float hn = (1.f - zg) * ng + zg * hold[rr];
            hold[rr] = hn;
            const int row = q * 4 + rr;
            hbuf[nxtb][row * 128 + (j ^ ((row & 7) << 3))] = (f16)hn;
        }
        __syncthreads();

        // coalesced global store of this step's h from hbuf[nxtb]
        {
            const int row = tid >> 5;
            const int ho = (tid & 31) * 4;
            const int idx = row * 128 + (ho ^ ((row & 7) << 3));
            const uint2 v = *reinterpret_cast<const uint2*>(&hbuf[nxtb][idx]);
            *reinterpret_cast<uint2*>(
                &hout[((size_t)tt * 2048 + row0 + row) * 128 + ho]) = v;
        }
    }
}

// ---------------------------------------------------------------------------
// K3a: byte attention scores. score[pos] = w2 . tanh(W1 @ out[pos] + b1) + b2
__global__ __launch_bounds__(256, 2) void k_scores(
    const __half* __restrict__ hF, const __half* __restrict__ hB,
    const float* __restrict__ w1T,  // [256][128]
    const float* __restrict__ b1, const float* __restrict__ w2,
    const float* __restrict__ b2, float* __restrict__ scores) {
    __shared__ float xs[128][33];
    __shared__ float wlds[32][128];
    const int tid = threadIdx.x;
    const int tk = tid & 15, tp = tid >> 4;
    const int k0 = tk * 8, p0 = tp * 8;
    const int pos0 = blockIdx.x * 128;

    float acc[8][8];
    #pragma unroll
    for (int q = 0; q < 8; ++q)
        #pragma unroll
        for (int p = 0; p < 8; ++p) acc[q][p] = 0.f;

    for (int dc = 0; dc < 8; ++dc) {
        __syncthreads();
        const __half* __restrict__ hsrc = (dc < 4) ? hF : hB;
        const int dbase = (dc & 3) * 32;
        const int dglob = (dc >> 2) * 128 + dbase;
        for (int i = tid; i < 128 * 32; i += 256) {
            const int pos = i >> 5, dl = i & 31;
            const int posg = pos0 + pos;
            const int l = posg >> 11, n = posg & 2047;
            xs[pos][dl] =
                __half2float(hsrc[((size_t)l * 2048 + n) * 128 + dbase + dl]);
        }
        for (int i = tid; i < 32 * 128; i += 256) {
            const int dd = i >> 7, k = i & 127;
            wlds[dd][k] = w1T[(dglob + dd) * 128 + k];
        }
        __syncthreads();
        for (int dd = 0; dd < 32; ++dd) {
            float xv[8], wv[8];
            #pragma unroll
            for (int p = 0; p < 8; ++p) xv[p] = xs[p0 + p][dd];
            #pragma unroll
            for (int q = 0; q < 8; ++q) wv[q] = wlds[dd][k0 + q];
            #pragma unroll
            for (int q = 0; q < 8; ++q)
                #pragma unroll
                for (int p = 0; p < 8; ++p)
                    acc[q][p] = fmaf(wv[q], xv[p], acc[q][p]);
        }
    }
    float b1v[8], w2v[8];
    #pragma unroll
    for (int q = 0; q < 8; ++q) { b1v[q] = b1[k0 + q]; w2v[q] = w2[k0 + q]; }
    const float b2v = b2[0];
    #pragma unroll
    for (int p = 0; p < 8; ++p) {
        float s = 0.f;
        #pragma unroll
        for (int q = 0; q < 8; ++q)
            s = fmaf(w2v[q], tanhf_fast(acc[q][p] + b1v[q]), s);
        s += __shfl_xor(s, 1);
        s += __shfl_xor(s, 2);
        s += __shfl_xor(s, 4);
        s += __shfl_xor(s, 8);
        if (tk == 0) scores[pos0 + p0 + p] = s + b2v;
    }
}

// ---------------------------------------------------------------------------
// K3a2: softmax over b (axis=2). grid 4096 = (l*32+p), block 64.
__global__ void k_attn_softmax(const float* __restrict__ scores,
                               float* __restrict__ attn) {
    const int lp = blockIdx.x;
    const float s = scores[lp * 64 + threadIdx.x];
    float m = s;
    for (int off = 32; off; off >>= 1) m = fmaxf(m, __shfl_xor(m, off));
    const float e = __expf(s - m);
    float sum = e;
    for (int off = 32; off; off >>= 1) sum += __shfl_xor(sum, off);
    attn[lp * 64 + threadIdx.x] = e / sum;
}

// ---------------------------------------------------------------------------
// K3b: packet_emb[p,b,d] = sum_l attn[l,p,b] * out[l,p,b,d]. grid 2048, block 256.
__global__ __launch_bounds__(256) void k_packet_emb(
    const __half* __restrict__ hF, const __half* __restrict__ hB,
    const float* __restrict__ attn, float* __restrict__ pe) {
    const int n = blockIdx.x;
    const int tid = threadIdx.x;
    const __half* __restrict__ hsrc = (tid < 128) ? hF : hB;
    const int d = tid & 127;
    float acc = 0.f;
    for (int l = 0; l < 128; ++l) {
        const float w = attn[l * 2048 + n];
        acc = fmaf(w, __half2float(hsrc[((size_t)l * 2048 + n) * 128 + d]), acc);
    }
    pe[n * 256 + tid] = acc;
}

// ---------------------------------------------------------------------------
// K4pre: xg2[p,n,g] = b_ih[g] + sum_d pe[p,n,d]*w_ih[g,d]. grid (256,2), block 384.
__global__ __launch_bounds__(384) void k_pkt_xg(
    const float* __restrict__ pe, const float* __restrict__ wihTF,
    const float* __restrict__ bihF, const float* __restrict__ wihTB,
    const float* __restrict__ bihB, float* __restrict__ xgF,
    float* __restrict__ xgB) {
    const int dir = blockIdx.y;
    const float* __restrict__ wihT = dir ? wihTB : wihTF;
    const float* __restrict__ bih = dir ? bihB : bihF;
    float* __restrict__ xg = dir ? xgB : xgF;
    const int rbase = blockIdx.x * 8;
    __shared__ float xrow[8][256];
    for (int i = threadIdx.x; i < 8 * 256; i += 384)
        xrow[i >> 8][i & 255] = pe[rbase * 256 + i];
    __syncthreads();
    const int g = threadIdx.x;
    float acc[8];
    #pragma unroll
    for (int r = 0; r < 8; ++r) acc[r] = bih[g];
    for (int d = 0; d < 256; ++d) {
        const float w = wihT[d * 384 + g];
        #pragma unroll
        for (int r = 0; r < 8; ++r) acc[r] = fmaf(w, xrow[r][d], acc[r]);
    }
    #pragma unroll
    for (int r = 0; r < 8; ++r) xg[(rbase + r) * 384 + g] = acc[r];
}

// ---------------------------------------------------------------------------
// K4: packet BiGRU. grid 32 (dir=bx&1, chunk=bx>>1: 4 rows), block 256, 32 steps.
__global__ __launch_bounds__(256, 1) void k_pkt_gru(
    const float* __restrict__ xgF, const float* __restrict__ xgB,
    const float* __restrict__ wTF, const float* __restrict__ wTB,
    const float* __restrict__ bhhF, const float* __restrict__ bhhB,
    float* __restrict__ h2F, float* __restrict__ h2B) {
    const int dir = blockIdx.x & 1;
    const int chunk = blockIdx.x >> 1;  // 0..15
    const int row0 = chunk * 4;
    const int tid = threadIdx.x;
    const int j = tid & 127;
    const int r0 = (tid >> 7) * 2;
    const float* __restrict__ xg = dir ? xgB : xgF;
    const float* __restrict__ wT = dir ? wTB : wTF;
    const float* __restrict__ bhh = dir ? bhhB : bhhF;
    float* __restrict__ hout = dir ? h2B : h2F;

    __shared__ float h_lds[4][128];
    #pragma unroll
    for (int r = 0; r < 2; ++r) h_lds[r0 + r][j] = 0.f;
    const float bh0 = bhh[j], bh1 = bhh[j + 128], bh2 = bhh[j + 256];
    __syncthreads();

    for (int t = 0; t < 32; ++t) {
        const int tt = dir ? (31 - t) : t;
        float a0[2], a1[2], a2[2];
        a0[0] = a0[1] = a1[0] = a1[1] = a2[0] = a2[1] = 0.f;
        #pragma unroll 2
        for (int hh = 0; hh < 128; hh += 4) {
            float4 hv[2];
            #pragma unroll
            for (int r = 0; r < 2; ++r)
                hv[r] = *reinterpret_cast<const float4*>(&h_lds[r0 + r][hh]);
            #pragma unroll
            for (int u = 0; u < 4; ++u) {
                const float* wrow = wT + (hh + u) * 384 + j;
                const float w0 = wrow[0], w1 = wrow[128], w2 = wrow[256];
                #pragma unroll
                for (int r = 0; r < 2; ++r) {
                    const float hvv = (&hv[r].x)[u];
                    a0[r] = fmaf(w0, hvv, a0[r]);
                    a1[r] = fmaf(w1, hvv, a1[r]);
                    a2[r] = fmaf(w2, hvv, a2[r]);
                }
            }
        }
        __syncthreads();
        #pragma unroll
        for (int r = 0; r < 2; ++r) {
            const int row = r0 + r;
            const int n = row0 + row;
            const float* xp = xg + ((size_t)tt * 64 + n) * 384 + j;
            const float xr = xp[0], xz = xp[128], xn = xp[256];
            const float rg = sigmoidf_fast(xr + a0[r] + bh0);
            const float zg = sigmoidf_fast(xz + a1[r] + bh1);
            const float ng = tanhf_fast(xn + rg * (a2[r] + bh2));
            const float hold = h_lds[row][j];
            const float hnew = (1.f - zg) * ng + zg * hold;
            h_lds[row][j] = hnew;
            hout[((size_t)tt * 64 + n) * 128 + j] = hnew;
        }
        __syncthreads();
    }
}

// ---------------------------------------------------------------------------
// K5: packet attention + softmax(axis=b) + weighted sum over b + final FC.
__global__ __launch_bounds__(256) void k_final(
    const float* __restrict__ h2F, const float* __restrict__ h2B,
    const float* __restrict__ paw1T,  // [256][128]
    const float* __restrict__ pab1, const float* __restrict__ paw2,
    const float* __restrict__ pab2, const float* __restrict__ wf,
    const float* __restrict__ bfv, float* __restrict__ outp) {
    const int p = blockIdx.x;
    const int tid = threadIdx.x;
    __shared__ float sc[64];
    __shared__ float red[64];
    __shared__ float femb[256];
    __shared__ float x2[2][256];

    const int k = tid & 127;
    const int bh = tid >> 7;
    const float b1v = pab1[k];
    const float w2v = paw2[k];

    for (int bb = 0; bb < 32; ++bb) {
        for (int i = tid; i < 512; i += 256) {
            const int bi = i >> 8, dd = i & 255;
            const int n = p * 64 + bb * 2 + bi;
            x2[bi][dd] = (dd < 128) ? h2F[n * 128 + dd] : h2B[n * 128 + dd - 128];
        }
        __syncthreads();
        float acc = 0.f;
        #pragma unroll 4
        for (int d = 0; d < 256; ++d)
            acc = fmaf(paw1T[d * 128 + k], x2[bh][d], acc);
        float s = w2v * tanhf_fast(acc + b1v);
        s += __shfl_xor(s, 1);
        s += __shfl_xor(s, 2);
        s += __shfl_xor(s, 4);
        s += __shfl_xor(s, 8);
        s += __shfl_xor(s, 16);
        s += __shfl_xor(s, 32);
        if ((tid & 63) == 0) red[tid >> 6] = s;
        __syncthreads();
        if (tid < 2) sc[bb * 2 + tid] = red[tid * 2] + red[tid * 2 + 1] + pab2[0];
        __syncthreads();
    }

    if (tid < 64) {
        const float s = sc[tid];
        float m = s;
        for (int off = 32; off; off >>= 1) m = fmaxf(m, __shfl_xor(m, off));
        const float e = __expf(s - m);
        float sum = e;
        for (int off = 32; off; off >>= 1) sum += __shfl_xor(sum, off);
        sc[tid] = e / sum;
    }
    __syncthreads();

    {
        const float* __restrict__ hsrc = (tid < 128) ? h2F : h2B;
        const int d = tid & 127;
        float acc = 0.f;
        for (int b = 0; b < 64; ++b)
            acc = fmaf(sc[b], hsrc[(p * 64 + b) * 128 + d], acc);
        femb[tid] = acc;
    }
    __syncthreads();

    const float fv = femb[tid];
    #pragma unroll
    for (int c = 0; c < 10; ++c) {
        float s = fv * wf[c * 256 + tid];
        s += __shfl_xor(s, 1);
        s += __shfl_xor(s, 2);
        s += __shfl_xor(s, 4);
        s += __shfl_xor(s, 8);
        s += __shfl_xor(s, 16);
        s += __shfl_xor(s, 32);
        if ((tid & 63) == 0) red[(c << 2) | (tid >> 6)] = s;
        __syncthreads();
        if (tid == 0)
            outp[p * 10 + c] = bfv[c] + red[c << 2] + red[(c << 2) | 1] +
                               red[(c << 2) | 2] + red[(c << 2) | 3];
        __syncthreads();
    }
}

// ---------------------------------------------------------------------------
extern "C" void kernel_launch(void* const* d_in, const int* in_sizes, int n_in,
                              void* d_out, int out_size, void* d_ws,
                              size_t ws_size, hipStream_t stream) {
    const int* flow = (const int*)d_in[0];
    const float* emb = (const float*)d_in[1];
    const float* byte_wih_f = (const float*)d_in[2];
    const float* byte_whh_f = (const float*)d_in[3];
    const float* byte_bih_f = (const float*)d_in[4];
    const float* byte_bhh_f = (const float*)d_in[5];
    const float* byte_wih_b = (const float*)d_in[6];
    const float* byte_whh_b = (const float*)d_in[7];
    const float* byte_bih_b = (const float*)d_in[8];
    const float* byte_bhh_b = (const float*)d_in[9];
    const float* pkt_wih_f = (const float*)d_in[10];
    const float* pkt_whh_f = (const float*)d_in[11];
    const float* pkt_bih_f = (const float*)d_in[12];
    const float* pkt_bhh_f = (const float*)d_in[13];
    const float* pkt_wih_b = (const float*)d_in[14];
    const float* pkt_whh_b = (const float*)d_in[15];
    const float* pkt_bih_b = (const float*)d_in[16];
    const float* pkt_bhh_b = (const float*)d_in[17];
    const float* ba_w1 = (const float*)d_in[18];
    const float* ba_b1 = (const float*)d_in[19];
    const float* ba_w2 = (const float*)d_in[20];
    const float* ba_b2 = (const float*)d_in[21];
    const float* pa_w1 = (const float*)d_in[22];
    const float* pa_b1 = (const float*)d_in[23];
    const float* pa_w2 = (const float*)d_in[24];
    const float* pa_b2 = (const float*)d_in[25];
    const float* wf = (const float*)d_in[26];
    const float* bf = (const float*)d_in[27];

    char* base = (char*)d_ws;
    size_t off = 0;
    auto allocf = [&](size_t nf) -> float* {
        float* p = (float*)(base + off);
        off += nf * sizeof(float);
        return p;
    };
    auto alloch = [&](size_t nh) -> __half* {
        __half* p = (__half*)(base + off);
        off += nh * sizeof(__half);
        off = (off + 15) & ~(size_t)15;
        return p;
    };
    float* tabF = allocf(256 * 384);
    float* tabB = allocf(256 * 384);
    float* wTpF = allocf(128 * 384);
    float* wTpB = allocf(128 * 384);
    float* wihTpF = allocf(256 * 384);
    float* wihTpB = allocf(256 * 384);
    float* baw1T = allocf(256 * 128);
    float* paw1T = allocf(256 * 128);
    float* scores = allocf(262144);
    float* attn = allocf(262144);
    float* pe = allocf(2048 * 256);
    float* xgF = allocf(32 * 64 * 384);
    float* xgB = allocf(32 * 64 * 384);
    float* h2F = allocf(32 * 64 * 128);
    float* h2B = allocf(32 * 64 * 128);
    __half* hF = alloch((size_t)128 * 2048 * 128);
    __half* hB = alloch((size_t)128 * 2048 * 128);
    if (off > ws_size) return;  // diagnostic: leaves d_out poisoned
    (void)in_sizes; (void)n_in; (void)out_size;

    k_tables<<<512, 384, 0, stream>>>(emb, byte_wih_f, byte_bih_f, byte_wih_b,
                                      byte_bih_b, tabF, tabB);

    TransArgs ta;
    ta.src[0] = pkt_whh_f;  ta.dst[0] = wTpF;   ta.R[0] = 384; ta.C[0] = 128;
    ta.src[1] = pkt_whh_b;  ta.dst[1] = wTpB;   ta.R[1] = 384; ta.C[1] = 128;
    ta.src[2] = pkt_wih_f;  ta.dst[2] = wihTpF; ta.R[2] = 384; ta.C[2] = 256;
    ta.src[3] = pkt_wih_b;  ta.dst[3] = wihTpB; ta.R[3] = 384; ta.C[3] = 256;
    ta.src[4] = ba_w1;      ta.dst[4] = baw1T;  ta.R[4] = 128; ta.C[4] = 256;
    ta.src[5] = pa_w1;      ta.dst[5] = paw1T;  ta.R[5] = 128; ta.C[5] = 256;
    k_transpose<<<dim3(96, 6), 256, 0, stream>>>(ta);

    k_byte_gru<<<256, 512, 0, stream>>>(flow, tabF, tabB, byte_whh_f,
                                        byte_whh_b, byte_bhh_f, byte_bhh_b, hF,
                                        hB);

    k_scores<<<2048, 256, 0, stream>>>(hF, hB, baw1T, ba_b1, ba_w2, ba_b2,
                                       scores);
    k_attn_softmax<<<4096, 64, 0, stream>>>(scores, attn);
    k_packet_emb<<<2048, 256, 0, stream>>>(hF, hB, attn, pe);

    k_pkt_xg<<<dim3(256, 2), 384, 0, stream>>>(pe, wihTpF, pkt_bih_f, wihTpB,
                                               pkt_bih_b, xgF, xgB);
    k_pkt_gru<<<32, 256, 0, stream>>>(xgF, xgB, wTpF, wTpB, pkt_bhh_f,
                                      pkt_bhh_b, h2F, h2B);
    k_final<<<32, 256, 0, stream>>>(h2F, h2B, paw1T, pa_b1, pa_w2, pa_b2, wf,
                                    bf, (float*)d_out);
}

// Round 4
// 536.209 us; speedup vs baseline: 3.8765x; 1.6605x over previous
//
#include <hip/hip_runtime.h>
#include <hip/hip_bf16.h>
#include <hip/hip_fp16.h>
#include <cstdint>
#include <cstddef>

// P=32, B=64, L=128, E=64, HB=128, HP=128, G=384, N=P*B=2048, PE=256, LH=128, NC=10

#define DINLINE __device__ __forceinline__

typedef _Float16 f16;
typedef f16 f16x8 __attribute__((ext_vector_type(8)));
typedef float f32x4 __attribute__((ext_vector_type(4)));

static DINLINE float sigmoidf_fast(float x) {
    return 1.0f / (1.0f + __expf(-x));
}
static DINLINE float tanhf_fast(float x) {
    float e2 = __expf(2.0f * x);
    return 1.0f - 2.0f / (e2 + 1.0f);
}

// ---------------------------------------------------------------------------
// K0a: byte tables: table[v][g] = b_ih[g] + sum_e emb[v][e]*w_ih[g][e]
__global__ void k_tables(const float* __restrict__ emb,
                         const float* __restrict__ wihF, const float* __restrict__ bihF,
                         const float* __restrict__ wihB, const float* __restrict__ bihB,
                         float* __restrict__ tabF, float* __restrict__ tabB) {
    const int v = blockIdx.x & 255;
    const int dir = blockIdx.x >> 8;
    const float* wih = dir ? wihB : wihF;
    const float* bih = dir ? bihB : bihF;
    float* tab = dir ? tabB : tabF;
    __shared__ float er[64];
    if (threadIdx.x < 64) er[threadIdx.x] = emb[v * 64 + threadIdx.x];
    __syncthreads();
    const int g = threadIdx.x;  // 384 threads
    float acc = bih[g];
    #pragma unroll
    for (int e = 0; e < 64; ++e) acc = fmaf(wih[g * 64 + e], er[e], acc);
    tab[v * 384 + g] = acc;
}

// ---------------------------------------------------------------------------
// K0b: transposes (4 matrices). out[c*R + r] = in[r*C + c]
struct TransArgs {
    const float* src[4];
    float* dst[4];
    int R[4];
    int C[4];
};
__global__ void k_transpose(TransArgs a) {
    const int m = blockIdx.y;
    const float* __restrict__ s = a.src[m];
    float* __restrict__ d = a.dst[m];
    const int R = a.R[m], C = a.C[m];
    const int total = R * C;
    for (int idx = blockIdx.x * blockDim.x + threadIdx.x; idx < total;
         idx += gridDim.x * blockDim.x) {
        const int r = idx / C, c = idx - r * C;
        d[c * R + r] = s[idx];
    }
}

// ---------------------------------------------------------------------------
// K2: byte BiGRU recurrence via MFMA f16 (verified fragment layout).
__global__ __launch_bounds__(512, 1) void k_byte_gru(
    const int* __restrict__ flow,
    const float* __restrict__ tabF, const float* __restrict__ tabB,
    const float* __restrict__ whhF, const float* __restrict__ whhB,
    const float* __restrict__ bhhF, const float* __restrict__ bhhB,
    __half* __restrict__ hF, __half* __restrict__ hB) {
    const int dir = blockIdx.x & 1;
    const int chunk = blockIdx.x >> 1;  // 0..127
    const int row0 = chunk * 16;
    const int tid = threadIdx.x;
    const int wid = tid >> 6;
    const int lane = tid & 63;
    const int c = lane & 15;
    const int q = lane >> 4;
    const int j = wid * 16 + c;  // h-col this lane produces

    const float* __restrict__ tab = dir ? tabB : tabF;
    const float* __restrict__ whh = dir ? whhB : whhF;
    const float* __restrict__ bhh = dir ? bhhB : bhhF;
    __half* __restrict__ hout = dir ? hB : hF;

    __shared__ f16 hbuf[2][16 * 128];  // swizzled: row*128 + (k ^ ((row&7)<<3))
    __shared__ int flow_lds[16][128];

    for (int i = tid; i < 16 * 128; i += 512)
        flow_lds[i >> 7][i & 127] = flow[row0 * 128 + i] & 255;
    for (int i = tid; i < 16 * 128; i += 512) hbuf[0][i] = (f16)0.f;

    // B fragments: B[k][col] = whh[(g*128+j)][k]; lane: col=lane&15, k=(lane>>4)*8+e+ks*32
    f16x8 Bf[3][4];
    #pragma unroll
    for (int g = 0; g < 3; ++g) {
        #pragma unroll
        for (int ks = 0; ks < 4; ++ks) {
            const float* src = whh + (size_t)(g * 128 + j) * 128 + ks * 32 + q * 8;
            f16x8 b;
            #pragma unroll
            for (int e = 0; e < 8; ++e) b[e] = (f16)src[e];
            Bf[g][ks] = b;
        }
    }
    const float bh0 = bhh[j], bh1 = bhh[j + 128], bh2 = bhh[j + 256];
    float hold[4];
    #pragma unroll
    for (int rr = 0; rr < 4; ++rr) hold[rr] = 0.f;
    __syncthreads();

    for (int t = 0; t < 128; ++t) {
        const int curb = t & 1, nxtb = curb ^ 1;
        const int tt = dir ? (127 - t) : t;

        int byt[4];
        #pragma unroll
        for (int rr = 0; rr < 4; ++rr) byt[rr] = flow_lds[q * 4 + rr][tt];
        float xr[4], xz[4], xn[4];
        #pragma unroll
        for (int rr = 0; rr < 4; ++rr) {
            const float* tb = tab + byt[rr] * 384 + j;
            xr[rr] = tb[0];
            xz[rr] = tb[128];
            xn[rr] = tb[256];
        }

        f16x8 Af[4];
        #pragma unroll
        for (int ks = 0; ks < 4; ++ks) {
            const int kb = ks * 32 + q * 8;
            const int idx = c * 128 + (kb ^ ((c & 7) << 3));
            Af[ks] = *reinterpret_cast<const f16x8*>(&hbuf[curb][idx]);
        }

        f32x4 a0 = {0.f, 0.f, 0.f, 0.f};
        f32x4 a1 = {0.f, 0.f, 0.f, 0.f};
        f32x4 a2 = {0.f, 0.f, 0.f, 0.f};
        #pragma unroll
        for (int ks = 0; ks < 4; ++ks) {
            a0 = __builtin_amdgcn_mfma_f32_16x16x32_f16(Af[ks], Bf[0][ks], a0, 0, 0, 0);
            a1 = __builtin_amdgcn_mfma_f32_16x16x32_f16(Af[ks], Bf[1][ks], a1, 0, 0, 0);
            a2 = __builtin_amdgcn_mfma_f32_16x16x32_f16(Af[ks], Bf[2][ks], a2, 0, 0, 0);
        }

        #pragma unroll
        for (int rr = 0; rr < 4; ++rr) {
            const float rg = sigmoidf_fast(xr[rr] + a0[rr] + bh0);
            const float zg = sigmoidf_fast(xz[rr] + a1[rr] + bh1);
            const float ng = tanhf_fast(xn[rr] + rg * (a2[rr] + bh2));
            const float hn = (1.f - zg) * ng + zg * hold[rr];
            hold[rr] = hn;
            const int row = q * 4 + rr;
            hbuf[nxtb][row * 128 + (j ^ ((row & 7) << 3))] = (f16)hn;
        }
        __syncthreads();

        {
            const int row = tid >> 5;
            const int ho = (tid & 31) * 4;
            const int idx = row * 128 + (ho ^ ((row & 7) << 3));
            const uint2 v = *reinterpret_cast<const uint2*>(&hbuf[nxtb][idx]);
            *reinterpret_cast<uint2*>(
                &hout[((size_t)tt * 2048 + row0 + row) * 128 + ho]) = v;
        }
    }
}

// ---------------------------------------------------------------------------
// K3a: byte attention scores via MFMA f16.
// grid 4096 (64 positions each), block 256 (4 waves, 16 rows/wave).
// score[pos] = w2 . tanh(W1 @ concat(hF,hB)[pos] + b1) + b2
__global__ __launch_bounds__(256, 1) void k_scores(
    const __half* __restrict__ hF, const __half* __restrict__ hB,
    const float* __restrict__ w1,  // [128][256] row-major (= B[col][k])
    const float* __restrict__ b1, const float* __restrict__ w2,
    const float* __restrict__ b2, float* __restrict__ scores) {
    __shared__ f16 w1lds[128 * 256];  // 64 KB, swizzled col*256 + (k ^ ((col&7)<<3))
    const int tid = threadIdx.x;
    for (int i = tid; i < 128 * 256; i += 256) {
        const int col = i >> 8, k = i & 255;
        w1lds[col * 256 + (k ^ ((col & 7) << 3))] = (f16)w1[i];
    }
    const int lane = tid & 63, w = tid >> 6;
    const int c = lane & 15, q = lane >> 4;
    const size_t pos = (size_t)blockIdx.x * 64 + w * 16 + c;

    // A fragments straight from global fp16 h (row = c, k = ks*32+q*8+e)
    f16x8 Af[8];
    const f16* hFp = (const f16*)(hF + pos * 128);
    const f16* hBp = (const f16*)(hB + pos * 128);
    #pragma unroll
    for (int ks = 0; ks < 4; ++ks)
        Af[ks] = *reinterpret_cast<const f16x8*>(hFp + ks * 32 + q * 8);
    #pragma unroll
    for (int ks = 0; ks < 4; ++ks)
        Af[4 + ks] = *reinterpret_cast<const f16x8*>(hBp + ks * 32 + q * 8);

    float b1v[8], w2v[8];
    #pragma unroll
    for (int ct = 0; ct < 8; ++ct) {
        b1v[ct] = b1[ct * 16 + c];
        w2v[ct] = w2[ct * 16 + c];
    }
    const float b2v = b2[0];
    __syncthreads();

    float s[4] = {0.f, 0.f, 0.f, 0.f};
    #pragma unroll
    for (int ct = 0; ct < 8; ++ct) {
        const int j = ct * 16 + c;
        f16x8 Bf[8];
        #pragma unroll
        for (int ks = 0; ks < 8; ++ks) {
            const int k = ks * 32 + q * 8;
            Bf[ks] = *reinterpret_cast<const f16x8*>(
                &w1lds[j * 256 + (k ^ ((j & 7) << 3))]);
        }
        f32x4 acc = {0.f, 0.f, 0.f, 0.f};
        #pragma unroll
        for (int ks = 0; ks < 8; ++ks)
            acc = __builtin_amdgcn_mfma_f32_16x16x32_f16(Af[ks], Bf[ks], acc, 0, 0, 0);
        #pragma unroll
        for (int rr = 0; rr < 4; ++rr)
            s[rr] += w2v[ct] * tanhf_fast(acc[rr] + b1v[ct]);
    }
    // reduce over col lanes (c) within each 16-lane group; C row = q*4+rr
    #pragma unroll
    for (int rr = 0; rr < 4; ++rr) {
        float v = s[rr];
        v += __shfl_xor(v, 1);
        v += __shfl_xor(v, 2);
        v += __shfl_xor(v, 4);
        v += __shfl_xor(v, 8);
        if (c == 0)
            scores[blockIdx.x * 64 + w * 16 + q * 4 + rr] = v + b2v;
    }
}

// ---------------------------------------------------------------------------
// K3a2: softmax over b (axis=2). grid 4096 = (l*32+p), block 64.
__global__ void k_attn_softmax(const float* __restrict__ scores,
                               float* __restrict__ attn) {
    const int lp = blockIdx.x;
    const float s = scores[lp * 64 + threadIdx.x];
    float m = s;
    for (int off = 32; off; off >>= 1) m = fmaxf(m, __shfl_xor(m, off));
    const float e = __expf(s - m);
    float sum = e;
    for (int off = 32; off; off >>= 1) sum += __shfl_xor(sum, off);
    attn[lp * 64 + threadIdx.x] = e / sum;
}

// ---------------------------------------------------------------------------
// K3b: packet_emb[p,b,d] = sum_l attn[l,p,b] * out[l,p,b,d]. grid 2048, block 256.
__global__ __launch_bounds__(256) void k_packet_emb(
    const __half* __restrict__ hF, const __half* __restrict__ hB,
    const float* __restrict__ attn, float* __restrict__ pe) {
    const int n = blockIdx.x;
    const int tid = threadIdx.x;
    const __half* __restrict__ hsrc = (tid < 128) ? hF : hB;
    const int d = tid & 127;
    float acc = 0.f;
    for (int l = 0; l < 128; ++l) {
        const float w = attn[l * 2048 + n];
        acc = fmaf(w, __half2float(hsrc[((size_t)l * 2048 + n) * 128 + d]), acc);
    }
    pe[n * 256 + tid] = acc;
}

// ---------------------------------------------------------------------------
// K4pre: xg2[p,n,g] = b_ih[g] + sum_d pe[p,n,d]*w_ih[g,d]. grid (256,2), block 384.
__global__ __launch_bounds__(384) void k_pkt_xg(
    const float* __restrict__ pe, const float* __restrict__ wihTF,
    const float* __restrict__ bihF, const float* __restrict__ wihTB,
    const float* __restrict__ bihB, float* __restrict__ xgF,
    float* __restrict__ xgB) {
    const int dir = blockIdx.y;
    const float* __restrict__ wihT = dir ? wihTB : wihTF;
    const float* __restrict__ bih = dir ? bihB : bihF;
    float* __restrict__ xg = dir ? xgB : xgF;
    const int rbase = blockIdx.x * 8;
    __shared__ float xrow[8][256];
    for (int i = threadIdx.x; i < 8 * 256; i += 384)
        xrow[i >> 8][i & 255] = pe[rbase * 256 + i];
    __syncthreads();
    const int g = threadIdx.x;
    float acc[8];
    #pragma unroll
    for (int r = 0; r < 8; ++r) acc[r] = bih[g];
    for (int d = 0; d < 256; ++d) {
        const float w = wihT[d * 384 + g];
        #pragma unroll
        for (int r = 0; r < 8; ++r) acc[r] = fmaf(w, xrow[r][d], acc[r]);
    }
    #pragma unroll
    for (int r = 0; r < 8; ++r) xg[(rbase + r) * 384 + g] = acc[r];
}

// ---------------------------------------------------------------------------
// K4: packet BiGRU. grid 32 (dir=bx&1, chunk=bx>>1: 4 rows), block 256, 32 steps.
__global__ __launch_bounds__(256, 1) void k_pkt_gru(
    const float* __restrict__ xgF, const float* __restrict__ xgB,
    const float* __restrict__ wTF, const float* __restrict__ wTB,
    const float* __restrict__ bhhF, const float* __restrict__ bhhB,
    float* __restrict__ h2F, float* __restrict__ h2B) {
    const int dir = blockIdx.x & 1;
    const int chunk = blockIdx.x >> 1;  // 0..15
    const int row0 = chunk * 4;
    const int tid = threadIdx.x;
    const int j = tid & 127;
    const int r0 = (tid >> 7) * 2;
    const float* __restrict__ xg = dir ? xgB : xgF;
    const float* __restrict__ wT = dir ? wTB : wTF;
    const float* __restrict__ bhh = dir ? bhhB : bhhF;
    float* __restrict__ hout = dir ? h2B : h2F;

    __shared__ float h_lds[4][128];
    #pragma unroll
    for (int r = 0; r < 2; ++r) h_lds[r0 + r][j] = 0.f;
    const float bh0 = bhh[j], bh1 = bhh[j + 128], bh2 = bhh[j + 256];
    __syncthreads();

    for (int t = 0; t < 32; ++t) {
        const int tt = dir ? (31 - t) : t;
        float a0[2], a1[2], a2[2];
        a0[0] = a0[1] = a1[0] = a1[1] = a2[0] = a2[1] = 0.f;
        #pragma unroll 2
        for (int hh = 0; hh < 128; hh += 4) {
            float4 hv[2];
            #pragma unroll
            for (int r = 0; r < 2; ++r)
                hv[r] = *reinterpret_cast<const float4*>(&h_lds[r0 + r][hh]);
            #pragma unroll
            for (int u = 0; u < 4; ++u) {
                const float* wrow = wT + (hh + u) * 384 + j;
                const float w0 = wrow[0], w1 = wrow[128], w2 = wrow[256];
                #pragma unroll
                for (int r = 0; r < 2; ++r) {
                    const float hvv = (&hv[r].x)[u];
                    a0[r] = fmaf(w0, hvv, a0[r]);
                    a1[r] = fmaf(w1, hvv, a1[r]);
                    a2[r] = fmaf(w2, hvv, a2[r]);
                }
            }
        }
        __syncthreads();
        #pragma unroll
        for (int r = 0; r < 2; ++r) {
            const int row = r0 + r;
            const int n = row0 + row;
            const float* xp = xg + ((size_t)tt * 64 + n) * 384 + j;
            const float xr = xp[0], xz = xp[128], xn = xp[256];
            const float rg = sigmoidf_fast(xr + a0[r] + bh0);
            const float zg = sigmoidf_fast(xz + a1[r] + bh1);
            const float ng = tanhf_fast(xn + rg * (a2[r] + bh2));
            const float hold = h_lds[row][j];
            const float hnew = (1.f - zg) * ng + zg * hold;
            h_lds[row][j] = hnew;
            hout[((size_t)tt * 64 + n) * 128 + j] = hnew;
        }
        __syncthreads();
    }
}

// ---------------------------------------------------------------------------
// K5a: packet attention scores. grid 2048 (n = p*64+b), block 128.
// scores2[n] = pa_w2 . tanh(pa_w1 @ concat(h2F,h2B)[n] + pa_b1) + pa_b2
__global__ __launch_bounds__(128) void k_scores2(
    const float* __restrict__ h2F, const float* __restrict__ h2B,
    const float* __restrict__ paw1,  // [128][256] row-major
    const float* __restrict__ pab1, const float* __restrict__ paw2,
    const float* __restrict__ pab2, float* __restrict__ scores2) {
    const int n = blockIdx.x;
    const int tid = threadIdx.x;  // 128
    __shared__ float x[256];
    __shared__ float red[2];
    x[tid] = h2F[n * 128 + tid];
    x[tid + 128] = h2B[n * 128 + tid];
    __syncthreads();
    float acc = pab1[tid];
    const float* wr = paw1 + tid * 256;
    #pragma unroll 8
    for (int d = 0; d < 256; ++d) acc = fmaf(wr[d], x[d], acc);
    float s = paw2[tid] * tanhf_fast(acc);
    s += __shfl_xor(s, 1);
    s += __shfl_xor(s, 2);
    s += __shfl_xor(s, 4);
    s += __shfl_xor(s, 8);
    s += __shfl_xor(s, 16);
    s += __shfl_xor(s, 32);
    if ((tid & 63) == 0) red[tid >> 6] = s;
    __syncthreads();
    if (tid == 0) scores2[n] = red[0] + red[1] + pab2[0];
}

// ---------------------------------------------------------------------------
// K5b: softmax over b + weighted sum + final FC. grid 32 (p), block 256.
__global__ __launch_bounds__(256) void k_final3(
    const float* __restrict__ h2F, const float* __restrict__ h2B,
    const float* __restrict__ scores2, const float* __restrict__ wf,
    const float* __restrict__ bfv, float* __restrict__ outp) {
    const int p = blockIdx.x;
    const int tid = threadIdx.x;
    __shared__ float sc[64];
    __shared__ float femb[256];
    __shared__ float red[64];

    if (tid < 64) {
        const float s = scores2[p * 64 + tid];
        float m = s;
        for (int off = 32; off; off >>= 1) m = fmaxf(m, __shfl_xor(m, off));
        const float e = __expf(s - m);
        float sum = e;
        for (int off = 32; off; off >>= 1) sum += __shfl_xor(sum, off);
        sc[tid] = e / sum;
    }
    __syncthreads();

    {
        const float* __restrict__ hsrc = (tid < 128) ? h2F : h2B;
        const int d = tid & 127;
        float acc = 0.f;
        for (int b = 0; b < 64; ++b)
            acc = fmaf(sc[b], hsrc[(p * 64 + b) * 128 + d], acc);
        femb[tid] = acc;
    }
    __syncthreads();

    const float fv = femb[tid];
    #pragma unroll
    for (int c = 0; c < 10; ++c) {
        float s = fv * wf[c * 256 + tid];
        s += __shfl_xor(s, 1);
        s += __shfl_xor(s, 2);
        s += __shfl_xor(s, 4);
        s += __shfl_xor(s, 8);
        s += __shfl_xor(s, 16);
        s += __shfl_xor(s, 32);
        if ((tid & 63) == 0) red[(c << 2) | (tid >> 6)] = s;
        __syncthreads();
        if (tid == 0)
            outp[p * 10 + c] = bfv[c] + red[c << 2] + red[(c << 2) | 1] +
                               red[(c << 2) | 2] + red[(c << 2) | 3];
        __syncthreads();
    }
}

// ---------------------------------------------------------------------------
extern "C" void kernel_launch(void* const* d_in, const int* in_sizes, int n_in,
                              void* d_out, int out_size, void* d_ws,
                              size_t ws_size, hipStream_t stream) {
    const int* flow = (const int*)d_in[0];
    const float* emb = (const float*)d_in[1];
    const float* byte_wih_f = (const float*)d_in[2];
    const float* byte_whh_f = (const float*)d_in[3];
    const float* byte_bih_f = (const float*)d_in[4];
    const float* byte_bhh_f = (const float*)d_in[5];
    const float* byte_wih_b = (const float*)d_in[6];
    const float* byte_whh_b = (const float*)d_in[7];
    const float* byte_bih_b = (const float*)d_in[8];
    const float* byte_bhh_b = (const float*)d_in[9];
    const float* pkt_wih_f = (const float*)d_in[10];
    const float* pkt_whh_f = (const float*)d_in[11];
    const float* pkt_bih_f = (const float*)d_in[12];
    const float* pkt_bhh_f = (const float*)d_in[13];
    const float* pkt_wih_b = (const float*)d_in[14];
    const float* pkt_whh_b = (const float*)d_in[15];
    const float* pkt_bih_b = (const float*)d_in[16];
    const float* pkt_bhh_b = (const float*)d_in[17];
    const float* ba_w1 = (const float*)d_in[18];
    const float* ba_b1 = (const float*)d_in[19];
    const float* ba_w2 = (const float*)d_in[20];
    const float* ba_b2 = (const float*)d_in[21];
    const float* pa_w1 = (const float*)d_in[22];
    const float* pa_b1 = (const float*)d_in[23];
    const float* pa_w2 = (const float*)d_in[24];
    const float* pa_b2 = (const float*)d_in[25];
    const float* wf = (const float*)d_in[26];
    const float* bf = (const float*)d_in[27];

    char* base = (char*)d_ws;
    size_t off = 0;
    auto allocf = [&](size_t nf) -> float* {
        float* p = (float*)(base + off);
        off += nf * sizeof(float);
        return p;
    };
    auto alloch = [&](size_t nh) -> __half* {
        __half* p = (__half*)(base + off);
        off += nh * sizeof(__half);
        off = (off + 15) & ~(size_t)15;
        return p;
    };
    float* tabF = allocf(256 * 384);
    float* tabB = allocf(256 * 384);
    float* wTpF = allocf(128 * 384);
    float* wTpB = allocf(128 * 384);
    float* wihTpF = allocf(256 * 384);
    float* wihTpB = allocf(256 * 384);
    float* scores = allocf(262144);
    float* attn = allocf(262144);
    float* pe = allocf(2048 * 256);
    float* xgF = allocf(32 * 64 * 384);
    float* xgB = allocf(32 * 64 * 384);
    float* h2F = allocf(32 * 64 * 128);
    float* h2B = allocf(32 * 64 * 128);
    float* scores2 = allocf(2048);
    __half* hF = alloch((size_t)128 * 2048 * 128);
    __half* hB = alloch((size_t)128 * 2048 * 128);
    if (off > ws_size) return;  // diagnostic: leaves d_out poisoned
    (void)in_sizes; (void)n_in; (void)out_size;

    k_tables<<<512, 384, 0, stream>>>(emb, byte_wih_f, byte_bih_f, byte_wih_b,
                                      byte_bih_b, tabF, tabB);

    TransArgs ta;
    ta.src[0] = pkt_whh_f;  ta.dst[0] = wTpF;   ta.R[0] = 384; ta.C[0] = 128;
    ta.src[1] = pkt_whh_b;  ta.dst[1] = wTpB;   ta.R[1] = 384; ta.C[1] = 128;
    ta.src[2] = pkt_wih_f;  ta.dst[2] = wihTpF; ta.R[2] = 384; ta.C[2] = 256;
    ta.src[3] = pkt_wih_b;  ta.dst[3] = wihTpB; ta.R[3] = 384; ta.C[3] = 256;
    k_transpose<<<dim3(96, 4), 256, 0, stream>>>(ta);

    k_byte_gru<<<256, 512, 0, stream>>>(flow, tabF, tabB, byte_whh_f,
                                        byte_whh_b, byte_bhh_f, byte_bhh_b, hF,
                                        hB);

    k_scores<<<4096, 256, 0, stream>>>(hF, hB, ba_w1, ba_b1, ba_w2, ba_b2,
                                       scores);
    k_attn_softmax<<<4096, 64, 0, stream>>>(scores, attn);
    k_packet_emb<<<2048, 256, 0, stream>>>(hF, hB, attn, pe);

    k_pkt_xg<<<dim3(256, 2), 384, 0, stream>>>(pe, wihTpF, pkt_bih_f, wihTpB,
                                               pkt_bih_b, xgF, xgB);
    k_pkt_gru<<<32, 256, 0, stream>>>(xgF, xgB, wTpF, wTpB, pkt_bhh_f,
                                      pkt_bhh_b, h2F, h2B);
    k_scores2<<<2048, 128, 0, stream>>>(h2F, h2B, pa_w1, pa_b1, pa_w2, pa_b2,
                                        scores2);
    k_final3<<<32, 256, 0, stream>>>(h2F, h2B, scores2, wf, bf, (float*)d_out);
}

// Round 5
// 450.256 us; speedup vs baseline: 4.6165x; 1.1909x over previous
//
#include <hip/hip_runtime.h>
#include <hip/hip_bf16.h>
#include <hip/hip_fp16.h>
#include <cstdint>
#include <cstddef>

// P=32, B=64, L=128, E=64, HB=128, HP=128, G=384, N=P*B=2048, PE=256, LH=128, NC=10

#define DINLINE __device__ __forceinline__

typedef _Float16 f16;
typedef f16 f16x8 __attribute__((ext_vector_type(8)));
typedef float f32x4 __attribute__((ext_vector_type(4)));

// raw-HW sigmoid/tanh: v_exp_f32 + v_rcp_f32 (1-ulp), no IEEE div sequence
static DINLINE float fast_sigmoid(float x) {
    const float e = __builtin_amdgcn_exp2f(-1.44269504089f * x);
    return __builtin_amdgcn_rcpf(1.0f + e);
}
static DINLINE float fast_tanh(float x) {
    const float e = __builtin_amdgcn_exp2f(2.88539008178f * x);
    return 1.0f - 2.0f * __builtin_amdgcn_rcpf(1.0f + e);
}

// ---------------------------------------------------------------------------
// K0a: byte tables: table[v][g] = b_ih[g] + sum_e emb[v][e]*w_ih[g][e]
//      (+ b_hh[g] folded in for the r,z gates g<256; n-gate bias stays runtime)
__global__ void k_tables(const float* __restrict__ emb,
                         const float* __restrict__ wihF, const float* __restrict__ bihF,
                         const float* __restrict__ bhhF,
                         const float* __restrict__ wihB, const float* __restrict__ bihB,
                         const float* __restrict__ bhhB,
                         float* __restrict__ tabF, float* __restrict__ tabB) {
    const int v = blockIdx.x & 255;
    const int dir = blockIdx.x >> 8;
    const float* wih = dir ? wihB : wihF;
    const float* bih = dir ? bihB : bihF;
    const float* bhh = dir ? bhhB : bhhF;
    float* tab = dir ? tabB : tabF;
    __shared__ float er[64];
    if (threadIdx.x < 64) er[threadIdx.x] = emb[v * 64 + threadIdx.x];
    __syncthreads();
    const int g = threadIdx.x;  // 384 threads
    float acc = bih[g] + (g < 256 ? bhh[g] : 0.0f);
    #pragma unroll
    for (int e = 0; e < 64; ++e) acc = fmaf(wih[g * 64 + e], er[e], acc);
    tab[v * 384 + g] = acc;
}

// ---------------------------------------------------------------------------
// K0b: transposes (4 matrices). out[c*R + r] = in[r*C + c]
struct TransArgs {
    const float* src[4];
    float* dst[4];
    int R[4];
    int C[4];
};
__global__ void k_transpose(TransArgs a) {
    const int m = blockIdx.y;
    const float* __restrict__ s = a.src[m];
    float* __restrict__ d = a.dst[m];
    const int R = a.R[m], C = a.C[m];
    const int total = R * C;
    for (int idx = blockIdx.x * blockDim.x + threadIdx.x; idx < total;
         idx += gridDim.x * blockDim.x) {
        const int r = idx / C, c = idx - r * C;
        d[c * R + r] = s[idx];
    }
}

// ---------------------------------------------------------------------------
// K2: byte BiGRU recurrence via MFMA f16.
__global__ __launch_bounds__(512, 1) void k_byte_gru(
    const int* __restrict__ flow,
    const float* __restrict__ tabF, const float* __restrict__ tabB,
    const float* __restrict__ whhF, const float* __restrict__ whhB,
    const float* __restrict__ bhhF, const float* __restrict__ bhhB,
    __half* __restrict__ hF, __half* __restrict__ hB) {
    const int dir = blockIdx.x & 1;
    const int chunk = blockIdx.x >> 1;  // 0..127
    const int row0 = chunk * 16;
    const int tid = threadIdx.x;
    const int wid = tid >> 6;
    const int lane = tid & 63;
    const int c = lane & 15;
    const int q = lane >> 4;
    const int j = wid * 16 + c;  // h-col this lane produces

    const float* __restrict__ tab = dir ? tabB : tabF;
    const float* __restrict__ whh = dir ? whhB : whhF;
    const float* __restrict__ bhh = dir ? bhhB : bhhF;
    __half* __restrict__ hout = dir ? hB : hF;

    __shared__ f16 hbuf[2][16 * 128];  // swizzled: row*128 + (k ^ ((row&7)<<3))
    __shared__ int flow_lds[16][128];

    for (int i = tid; i < 16 * 128; i += 512)
        flow_lds[i >> 7][i & 127] = flow[row0 * 128 + i] & 255;
    for (int i = tid; i < 16 * 128; i += 512) hbuf[0][i] = (f16)0.f;

    // B fragments: B[k][col] = whh[(g*128+j)][k]; lane: col=lane&15, k=(lane>>4)*8+e+ks*32
    f16x8 Bf[3][4];
    #pragma unroll
    for (int g = 0; g < 3; ++g) {
        #pragma unroll
        for (int ks = 0; ks < 4; ++ks) {
            const float* src = whh + (size_t)(g * 128 + j) * 128 + ks * 32 + q * 8;
            f16x8 b;
            #pragma unroll
            for (int e = 0; e < 8; ++e) b[e] = (f16)src[e];
            Bf[g][ks] = b;
        }
    }
    const float bh2 = bhh[j + 256];  // r,z biases folded into tab
    float hold[4];
    #pragma unroll
    for (int rr = 0; rr < 4; ++rr) hold[rr] = 0.f;
    __syncthreads();

    for (int t = 0; t < 128; ++t) {
        const int curb = t & 1, nxtb = curb ^ 1;
        const int tt = dir ? (127 - t) : t;

        int byt[4];
        #pragma unroll
        for (int rr = 0; rr < 4; ++rr) byt[rr] = flow_lds[q * 4 + rr][tt];
        float xr[4], xz[4], xn[4];
        #pragma unroll
        for (int rr = 0; rr < 4; ++rr) {
            const float* tb = tab + byt[rr] * 384 + j;
            xr[rr] = tb[0];
            xz[rr] = tb[128];
            xn[rr] = tb[256];
        }

        f16x8 Af[4];
        #pragma unroll
        for (int ks = 0; ks < 4; ++ks) {
            const int kb = ks * 32 + q * 8;
            const int idx = c * 128 + (kb ^ ((c & 7) << 3));
            Af[ks] = *reinterpret_cast<const f16x8*>(&hbuf[curb][idx]);
        }

        f32x4 a0 = {0.f, 0.f, 0.f, 0.f};
        f32x4 a1 = {0.f, 0.f, 0.f, 0.f};
        f32x4 a2 = {0.f, 0.f, 0.f, 0.f};
        #pragma unroll
        for (int ks = 0; ks < 4; ++ks) {
            a0 = __builtin_amdgcn_mfma_f32_16x16x32_f16(Af[ks], Bf[0][ks], a0, 0, 0, 0);
            a1 = __builtin_amdgcn_mfma_f32_16x16x32_f16(Af[ks], Bf[1][ks], a1, 0, 0, 0);
            a2 = __builtin_amdgcn_mfma_f32_16x16x32_f16(Af[ks], Bf[2][ks], a2, 0, 0, 0);
        }

        #pragma unroll
        for (int rr = 0; rr < 4; ++rr) {
            const float rg = fast_sigmoid(xr[rr] + a0[rr]);
            const float zg = fast_sigmoid(xz[rr] + a1[rr]);
            const float ng = fast_tanh(xn[rr] + rg * (a2[rr] + bh2));
            const float hn = fmaf(zg, hold[rr] - ng, ng);
            hold[rr] = hn;
            const int row = q * 4 + rr;
            hbuf[nxtb][row * 128 + (j ^ ((row & 7) << 3))] = (f16)hn;
        }
        __syncthreads();

        {
            const int row = tid >> 5;
            const int ho = (tid & 31) * 4;
            const int idx = row * 128 + (ho ^ ((row & 7) << 3));
            const uint2 v = *reinterpret_cast<const uint2*>(&hbuf[nxtb][idx]);
            *reinterpret_cast<uint2*>(
                &hout[((size_t)tt * 2048 + row0 + row) * 128 + ho]) = v;
        }
    }
}

// ---------------------------------------------------------------------------
// K3: byte attention scores + softmax fused.
// grid 2048 (128 positions = 2 complete (l,p) softmax groups), block 256.
__global__ __launch_bounds__(256, 1) void k_scores_attn(
    const __half* __restrict__ hF, const __half* __restrict__ hB,
    const float* __restrict__ w1,  // [128][256] row-major (= B[col][k])
    const float* __restrict__ b1, const float* __restrict__ w2,
    const float* __restrict__ b2, float* __restrict__ attn) {
    __shared__ f16 w1lds[128 * 256];  // 64 KB, swizzled col*256 + (k ^ ((col&7)<<3))
    __shared__ float sc[128];
    const int tid = threadIdx.x;
    for (int i = tid; i < 128 * 256; i += 256) {
        const int col = i >> 8, k = i & 255;
        w1lds[col * 256 + (k ^ ((col & 7) << 3))] = (f16)w1[i];
    }
    const int lane = tid & 63, w = tid >> 6;
    const int c = lane & 15, q = lane >> 4;
    const int pos0 = blockIdx.x * 128;

    // wave w handles position tiles pt = 2w, 2w+1 (16 positions each)
    f16x8 Af[2][8];
    #pragma unroll
    for (int pt = 0; pt < 2; ++pt) {
        const size_t pos = (size_t)pos0 + (w * 2 + pt) * 16 + c;
        const f16* hFp = (const f16*)(hF + pos * 128);
        const f16* hBp = (const f16*)(hB + pos * 128);
        #pragma unroll
        for (int ks = 0; ks < 4; ++ks)
            Af[pt][ks] = *reinterpret_cast<const f16x8*>(hFp + ks * 32 + q * 8);
        #pragma unroll
        for (int ks = 0; ks < 4; ++ks)
            Af[pt][4 + ks] = *reinterpret_cast<const f16x8*>(hBp + ks * 32 + q * 8);
    }

    float b1v[8], w2v[8];
    #pragma unroll
    for (int ct = 0; ct < 8; ++ct) {
        b1v[ct] = b1[ct * 16 + c];
        w2v[ct] = w2[ct * 16 + c];
    }
    const float b2v = b2[0];
    __syncthreads();

    float s[2][4] = {{0.f, 0.f, 0.f, 0.f}, {0.f, 0.f, 0.f, 0.f}};
    #pragma unroll
    for (int ct = 0; ct < 8; ++ct) {
        const int jj = ct * 16 + c;
        f16x8 Bfr[8];
        #pragma unroll
        for (int ks = 0; ks < 8; ++ks) {
            const int k = ks * 32 + q * 8;
            Bfr[ks] = *reinterpret_cast<const f16x8*>(
                &w1lds[jj * 256 + (k ^ ((jj & 7) << 3))]);
        }
        #pragma unroll
        for (int pt = 0; pt < 2; ++pt) {
            f32x4 acc = {0.f, 0.f, 0.f, 0.f};
            #pragma unroll
            for (int ks = 0; ks < 8; ++ks)
                acc = __builtin_amdgcn_mfma_f32_16x16x32_f16(Af[pt][ks], Bfr[ks],
                                                             acc, 0, 0, 0);
            #pragma unroll
            for (int rr = 0; rr < 4; ++rr)
                s[pt][rr] += w2v[ct] * fast_tanh(acc[rr] + b1v[ct]);
        }
    }
    #pragma unroll
    for (int pt = 0; pt < 2; ++pt) {
        #pragma unroll
        for (int rr = 0; rr < 4; ++rr) {
            float v = s[pt][rr];
            v += __shfl_xor(v, 1);
            v += __shfl_xor(v, 2);
            v += __shfl_xor(v, 4);
            v += __shfl_xor(v, 8);
            if (c == 0) sc[(w * 2 + pt) * 16 + q * 4 + rr] = v + b2v;
        }
    }
    __syncthreads();
    // softmax over b: groups of 64 (tid 0..63 = group 0 wave, 64..127 = group 1)
    if (tid < 128) {
        const float sv = sc[tid];
        float m = sv;
        for (int off = 32; off; off >>= 1) m = fmaxf(m, __shfl_xor(m, off));
        const float e = __expf(sv - m);
        float sum = e;
        for (int off = 32; off; off >>= 1) sum += __shfl_xor(sum, off);
        attn[pos0 + tid] = e / sum;
    }
}

// ---------------------------------------------------------------------------
// K3b: packet_emb[n,d] = sum_l attn[l,n] * h[l,n,d]. grid 512 (4 n each), block 256.
__global__ __launch_bounds__(256) void k_packet_emb(
    const __half* __restrict__ hF, const __half* __restrict__ hB,
    const float* __restrict__ attn, float* __restrict__ pe) {
    const int tid = threadIdx.x;
    const int g = tid >> 6;          // n group
    const int lane = tid & 63;
    const int n = blockIdx.x * 4 + g;
    const bool isF = lane < 32;
    const int chunk = lane & 31;     // 4 f16 per chunk
    const __half* __restrict__ hsrc = (isF ? hF : hB) + (size_t)n * 128 + chunk * 4;
    float acc0 = 0.f, acc1 = 0.f, acc2 = 0.f, acc3 = 0.f;
    #pragma unroll 4
    for (int l = 0; l < 128; ++l) {
        const float wv = attn[l * 2048 + n];
        const uint2 u = *reinterpret_cast<const uint2*>(hsrc + (size_t)l * 2048 * 128);
        const f16* hv = reinterpret_cast<const f16*>(&u);
        acc0 = fmaf(wv, (float)hv[0], acc0);
        acc1 = fmaf(wv, (float)hv[1], acc1);
        acc2 = fmaf(wv, (float)hv[2], acc2);
        acc3 = fmaf(wv, (float)hv[3], acc3);
    }
    float4 o = {acc0, acc1, acc2, acc3};
    *reinterpret_cast<float4*>(&pe[n * 256 + (isF ? 0 : 128) + chunk * 4]) = o;
}

// ---------------------------------------------------------------------------
// K4pre: xg2[p,n,g] = b_ih[g] + sum_d pe[p,n,d]*w_ih[g,d]. grid (256,2), block 384.
__global__ __launch_bounds__(384) void k_pkt_xg(
    const float* __restrict__ pe, const float* __restrict__ wihTF,
    const float* __restrict__ bihF, const float* __restrict__ wihTB,
    const float* __restrict__ bihB, float* __restrict__ xgF,
    float* __restrict__ xgB) {
    const int dir = blockIdx.y;
    const float* __restrict__ wihT = dir ? wihTB : wihTF;
    const float* __restrict__ bih = dir ? bihB : bihF;
    float* __restrict__ xg = dir ? xgB : xgF;
    const int rbase = blockIdx.x * 8;
    __shared__ float xrow[8][256];
    for (int i = threadIdx.x; i < 8 * 256; i += 384)
        xrow[i >> 8][i & 255] = pe[rbase * 256 + i];
    __syncthreads();
    const int g = threadIdx.x;
    float acc[8];
    #pragma unroll
    for (int r = 0; r < 8; ++r) acc[r] = bih[g];
    for (int d = 0; d < 256; ++d) {
        const float w = wihT[d * 384 + g];
        #pragma unroll
        for (int r = 0; r < 8; ++r) acc[r] = fmaf(w, xrow[r][d], acc[r]);
    }
    #pragma unroll
    for (int r = 0; r < 8; ++r) xg[(rbase + r) * 384 + g] = acc[r];
}

// ---------------------------------------------------------------------------
// K4: packet BiGRU. grid 32 (dir=bx&1, chunk=bx>>1: 4 rows), block 256, 32 steps.
__global__ __launch_bounds__(256, 1) void k_pkt_gru(
    const float* __restrict__ xgF, const float* __restrict__ xgB,
    const float* __restrict__ wTF, const float* __restrict__ wTB,
    const float* __restrict__ bhhF, const float* __restrict__ bhhB,
    float* __restrict__ h2F, float* __restrict__ h2B) {
    const int dir = blockIdx.x & 1;
    const int chunk = blockIdx.x >> 1;  // 0..15
    const int row0 = chunk * 4;
    const int tid = threadIdx.x;
    const int j = tid & 127;
    const int r0 = (tid >> 7) * 2;
    const float* __restrict__ xg = dir ? xgB : xgF;
    const float* __restrict__ wT = dir ? wTB : wTF;
    const float* __restrict__ bhh = dir ? bhhB : bhhF;
    float* __restrict__ hout = dir ? h2B : h2F;

    __shared__ float h_lds[4][128];
    #pragma unroll
    for (int r = 0; r < 2; ++r) h_lds[r0 + r][j] = 0.f;
    const float bh0 = bhh[j], bh1 = bhh[j + 128], bh2 = bhh[j + 256];
    __syncthreads();

    for (int t = 0; t < 32; ++t) {
        const int tt = dir ? (31 - t) : t;
        float a0[2], a1[2], a2[2];
        a0[0] = a0[1] = a1[0] = a1[1] = a2[0] = a2[1] = 0.f;
        #pragma unroll 2
        for (int hh = 0; hh < 128; hh += 4) {
            float4 hv[2];
            #pragma unroll
            for (int r = 0; r < 2; ++r)
                hv[r] = *reinterpret_cast<const float4*>(&h_lds[r0 + r][hh]);
            #pragma unroll
            for (int u = 0; u < 4; ++u) {
                const float* wrow = wT + (hh + u) * 384 + j;
                const float w0 = wrow[0], w1 = wrow[128], w2 = wrow[256];
                #pragma unroll
                for (int r = 0; r < 2; ++r) {
                    const float hvv = (&hv[r].x)[u];
                    a0[r] = fmaf(w0, hvv, a0[r]);
                    a1[r] = fmaf(w1, hvv, a1[r]);
                    a2[r] = fmaf(w2, hvv, a2[r]);
                }
            }
        }
        __syncthreads();
        #pragma unroll
        for (int r = 0; r < 2; ++r) {
            const int row = r0 + r;
            const int n = row0 + row;
            const float* xp = xg + ((size_t)tt * 64 + n) * 384 + j;
            const float xr = xp[0], xz = xp[128], xn = xp[256];
            const float rg = fast_sigmoid(xr + a0[r] + bh0);
            const float zg = fast_sigmoid(xz + a1[r] + bh1);
            const float ng = fast_tanh(xn + rg * (a2[r] + bh2));
            const float hold = h_lds[row][j];
            const float hnew = fmaf(zg, hold - ng, ng);
            h_lds[row][j] = hnew;
            hout[((size_t)tt * 64 + n) * 128 + j] = hnew;
        }
        __syncthreads();
    }
}

// ---------------------------------------------------------------------------
// K5a: packet attention scores. grid 2048 (n), block 128.
__global__ __launch_bounds__(128) void k_scores2(
    const float* __restrict__ h2F, const float* __restrict__ h2B,
    const float* __restrict__ paw1,  // [128][256] row-major
    const float* __restrict__ pab1, const float* __restrict__ paw2,
    const float* __restrict__ pab2, float* __restrict__ scores2) {
    const int n = blockIdx.x;
    const int tid = threadIdx.x;  // 128
    __shared__ float x[256];
    __shared__ float red[2];
    x[tid] = h2F[n * 128 + tid];
    x[tid + 128] = h2B[n * 128 + tid];
    __syncthreads();
    float acc = pab1[tid];
    const float* wr = paw1 + tid * 256;
    #pragma unroll 8
    for (int d = 0; d < 256; ++d) acc = fmaf(wr[d], x[d], acc);
    float s = paw2[tid] * fast_tanh(acc);
    s += __shfl_xor(s, 1);
    s += __shfl_xor(s, 2);
    s += __shfl_xor(s, 4);
    s += __shfl_xor(s, 8);
    s += __shfl_xor(s, 16);
    s += __shfl_xor(s, 32);
    if ((tid & 63) == 0) red[tid >> 6] = s;
    __syncthreads();
    if (tid == 0) scores2[n] = red[0] + red[1] + pab2[0];
}

// ---------------------------------------------------------------------------
// K5b: softmax over b + weighted sum + final FC. grid 32 (p), block 256.
__global__ __launch_bounds__(256) void k_final3(
    const float* __restrict__ h2F, const float* __restrict__ h2B,
    const float* __restrict__ scores2, const float* __restrict__ wf,
    const float* __restrict__ bfv, float* __restrict__ outp) {
    const int p = blockIdx.x;
    const int tid = threadIdx.x;
    __shared__ float sc[64];
    __shared__ float femb[256];
    __shared__ float red[64];

    if (tid < 64) {
        const float s = scores2[p * 64 + tid];
        float m = s;
        for (int off = 32; off; off >>= 1) m = fmaxf(m, __shfl_xor(m, off));
        const float e = __expf(s - m);
        float sum = e;
        for (int off = 32; off; off >>= 1) sum += __shfl_xor(sum, off);
        sc[tid] = e / sum;
    }
    __syncthreads();

    {
        const float* __restrict__ hsrc = (tid < 128) ? h2F : h2B;
        const int d = tid & 127;
        float acc = 0.f;
        for (int b = 0; b < 64; ++b)
            acc = fmaf(sc[b], hsrc[(p * 64 + b) * 128 + d], acc);
        femb[tid] = acc;
    }
    __syncthreads();

    const float fv = femb[tid];
    #pragma unroll
    for (int c = 0; c < 10; ++c) {
        float s = fv * wf[c * 256 + tid];
        s += __shfl_xor(s, 1);
        s += __shfl_xor(s, 2);
        s += __shfl_xor(s, 4);
        s += __shfl_xor(s, 8);
        s += __shfl_xor(s, 16);
        s += __shfl_xor(s, 32);
        if ((tid & 63) == 0) red[(c << 2) | (tid >> 6)] = s;
        __syncthreads();
        if (tid == 0)
            outp[p * 10 + c] = bfv[c] + red[c << 2] + red[(c << 2) | 1] +
                               red[(c << 2) | 2] + red[(c << 2) | 3];
        __syncthreads();
    }
}

// ---------------------------------------------------------------------------
extern "C" void kernel_launch(void* const* d_in, const int* in_sizes, int n_in,
                              void* d_out, int out_size, void* d_ws,
                              size_t ws_size, hipStream_t stream) {
    const int* flow = (const int*)d_in[0];
    const float* emb = (const float*)d_in[1];
    const float* byte_wih_f = (const float*)d_in[2];
    const float* byte_whh_f = (const float*)d_in[3];
    const float* byte_bih_f = (const float*)d_in[4];
    const float* byte_bhh_f = (const float*)d_in[5];
    const float* byte_wih_b = (const float*)d_in[6];
    const float* byte_whh_b = (const float*)d_in[7];
    const float* byte_bih_b = (const float*)d_in[8];
    const float* byte_bhh_b = (const float*)d_in[9];
    const float* pkt_wih_f = (const float*)d_in[10];
    const float* pkt_whh_f = (const float*)d_in[11];
    const float* pkt_bih_f = (const float*)d_in[12];
    const float* pkt_bhh_f = (const float*)d_in[13];
    const float* pkt_wih_b = (const float*)d_in[14];
    const float* pkt_whh_b = (const float*)d_in[15];
    const float* pkt_bih_b = (const float*)d_in[16];
    const float* pkt_bhh_b = (const float*)d_in[17];
    const float* ba_w1 = (const float*)d_in[18];
    const float* ba_b1 = (const float*)d_in[19];
    const float* ba_w2 = (const float*)d_in[20];
    const float* ba_b2 = (const float*)d_in[21];
    const float* pa_w1 = (const float*)d_in[22];
    const float* pa_b1 = (const float*)d_in[23];
    const float* pa_w2 = (const float*)d_in[24];
    const float* pa_b2 = (const float*)d_in[25];
    const float* wf = (const float*)d_in[26];
    const float* bf = (const float*)d_in[27];

    char* base = (char*)d_ws;
    size_t off = 0;
    auto allocf = [&](size_t nf) -> float* {
        float* p = (float*)(base + off);
        off += nf * sizeof(float);
        return p;
    };
    auto alloch = [&](size_t nh) -> __half* {
        off = (off + 255) & ~(size_t)255;
        __half* p = (__half*)(base + off);
        off += nh * sizeof(__half);
        return p;
    };
    float* tabF = allocf(256 * 384);
    float* tabB = allocf(256 * 384);
    float* wTpF = allocf(128 * 384);
    float* wTpB = allocf(128 * 384);
    float* wihTpF = allocf(256 * 384);
    float* wihTpB = allocf(256 * 384);
    float* attn = allocf(262144);
    float* pe = allocf(2048 * 256);
    float* xgF = allocf(32 * 64 * 384);
    float* xgB = allocf(32 * 64 * 384);
    float* h2F = allocf(32 * 64 * 128);
    float* h2B = allocf(32 * 64 * 128);
    float* scores2 = allocf(2048);
    __half* hF = alloch((size_t)128 * 2048 * 128);
    __half* hB = alloch((size_t)128 * 2048 * 128);
    if (off > ws_size) return;  // diagnostic: leaves d_out poisoned
    (void)in_sizes; (void)n_in; (void)out_size;

    k_tables<<<512, 384, 0, stream>>>(emb, byte_wih_f, byte_bih_f, byte_bhh_f,
                                      byte_wih_b, byte_bih_b, byte_bhh_b, tabF,
                                      tabB);

    TransArgs ta;
    ta.src[0] = pkt_whh_f;  ta.dst[0] = wTpF;   ta.R[0] = 384; ta.C[0] = 128;
    ta.src[1] = pkt_whh_b;  ta.dst[1] = wTpB;   ta.R[1] = 384; ta.C[1] = 128;
    ta.src[2] = pkt_wih_f;  ta.dst[2] = wihTpF; ta.R[2] = 384; ta.C[2] = 256;
    ta.src[3] = pkt_wih_b;  ta.dst[3] = wihTpB; ta.R[3] = 384; ta.C[3] = 256;
    k_transpose<<<dim3(96, 4), 256, 0, stream>>>(ta);

    k_byte_gru<<<256, 512, 0, stream>>>(flow, tabF, tabB, byte_whh_f,
                                        byte_whh_b, byte_bhh_f, byte_bhh_b, hF,
                                        hB);

    k_scores_attn<<<2048, 256, 0, stream>>>(hF, hB, ba_w1, ba_b1, ba_w2, ba_b2,
                                            attn);
    k_packet_emb<<<512, 256, 0, stream>>>(hF, hB, attn, pe);

    k_pkt_xg<<<dim3(256, 2), 384, 0, stream>>>(pe, wihTpF, pkt_bih_f, wihTpB,
                                               pkt_bih_b, xgF, xgB);
    k_pkt_gru<<<32, 256, 0, stream>>>(xgF, xgB, wTpF, wTpB, pkt_bhh_f,
                                      pkt_bhh_b, h2F, h2B);
    k_scores2<<<2048, 128, 0, stream>>>(h2F, h2B, pa_w1, pa_b1, pa_w2, pa_b2,
                                        scores2);
    k_final3<<<32, 256, 0, stream>>>(h2F, h2B, scores2, wf, bf, (float*)d_out);
}

// Round 6
// 315.559 us; speedup vs baseline: 6.5871x; 1.4269x over previous
//
#include <hip/hip_runtime.h>
#include <hip/hip_bf16.h>
#include <hip/hip_fp16.h>
#include <cstdint>
#include <cstddef>

// P=32, B=64, L=128, E=64, HB=128, HP=128, G=384, N=P*B=2048, PE=256, LH=128, NC=10

#define DINLINE __device__ __forceinline__

typedef _Float16 f16;
typedef f16 f16x8 __attribute__((ext_vector_type(8)));
typedef float f32x4 __attribute__((ext_vector_type(4)));

// raw-HW sigmoid/tanh: v_exp_f32 + v_rcp_f32 (1-ulp), no IEEE div sequence
static DINLINE float fast_sigmoid(float x) {
    const float e = __builtin_amdgcn_exp2f(-1.44269504089f * x);
    return __builtin_amdgcn_rcpf(1.0f + e);
}
static DINLINE float fast_tanh(float x) {
    const float e = __builtin_amdgcn_exp2f(2.88539008178f * x);
    return 1.0f - 2.0f * __builtin_amdgcn_rcpf(1.0f + e);
}

// ---------------------------------------------------------------------------
// K0a: byte tables: table[v][g] = b_ih[g] + sum_e emb[v][e]*w_ih[g][e]
//      (+ b_hh[g] folded in for the r,z gates g<256)
__global__ void k_tables(const float* __restrict__ emb,
                         const float* __restrict__ wihF, const float* __restrict__ bihF,
                         const float* __restrict__ bhhF,
                         const float* __restrict__ wihB, const float* __restrict__ bihB,
                         const float* __restrict__ bhhB,
                         float* __restrict__ tabF, float* __restrict__ tabB) {
    const int v = blockIdx.x & 255;
    const int dir = blockIdx.x >> 8;
    const float* wih = dir ? wihB : wihF;
    const float* bih = dir ? bihB : bihF;
    const float* bhh = dir ? bhhB : bhhF;
    float* tab = dir ? tabB : tabF;
    __shared__ float er[64];
    if (threadIdx.x < 64) er[threadIdx.x] = emb[v * 64 + threadIdx.x];
    __syncthreads();
    const int g = threadIdx.x;  // 384 threads
    float acc = bih[g] + (g < 256 ? bhh[g] : 0.0f);
    #pragma unroll
    for (int e = 0; e < 64; ++e) acc = fmaf(wih[g * 64 + e], er[e], acc);
    tab[v * 384 + g] = acc;
}

// ---------------------------------------------------------------------------
// K0b: transposes (2 matrices). out[c*R + r] = in[r*C + c]
struct TransArgs {
    const float* src[2];
    float* dst[2];
    int R[2];
    int C[2];
};
__global__ void k_transpose(TransArgs a) {
    const int m = blockIdx.y;
    const float* __restrict__ s = a.src[m];
    float* __restrict__ d = a.dst[m];
    const int R = a.R[m], C = a.C[m];
    const int total = R * C;
    for (int idx = blockIdx.x * blockDim.x + threadIdx.x; idx < total;
         idx += gridDim.x * blockDim.x) {
        const int r = idx / C, c = idx - r * C;
        d[c * R + r] = s[idx];
    }
}

// ---------------------------------------------------------------------------
// K2: byte BiGRU recurrence via MFMA f16.
__global__ __launch_bounds__(512, 1) void k_byte_gru(
    const int* __restrict__ flow,
    const float* __restrict__ tabF, const float* __restrict__ tabB,
    const float* __restrict__ whhF, const float* __restrict__ whhB,
    const float* __restrict__ bhhF, const float* __restrict__ bhhB,
    __half* __restrict__ hF, __half* __restrict__ hB) {
    const int dir = blockIdx.x & 1;
    const int chunk = blockIdx.x >> 1;  // 0..127
    const int row0 = chunk * 16;
    const int tid = threadIdx.x;
    const int wid = tid >> 6;
    const int lane = tid & 63;
    const int c = lane & 15;
    const int q = lane >> 4;
    const int j = wid * 16 + c;  // h-col this lane produces

    const float* __restrict__ tab = dir ? tabB : tabF;
    const float* __restrict__ whh = dir ? whhB : whhF;
    const float* __restrict__ bhh = dir ? bhhB : bhhF;
    __half* __restrict__ hout = dir ? hB : hF;

    __shared__ f16 hbuf[2][16 * 128];  // swizzled: row*128 + (k ^ ((row&7)<<3))
    __shared__ int flow_lds[16][128];

    for (int i = tid; i < 16 * 128; i += 512)
        flow_lds[i >> 7][i & 127] = flow[row0 * 128 + i] & 255;
    for (int i = tid; i < 16 * 128; i += 512) hbuf[0][i] = (f16)0.f;

    // B fragments: B[k][col] = whh[(g*128+j)][k]; lane: col=lane&15, k=(lane>>4)*8+e+ks*32
    f16x8 Bf[3][4];
    #pragma unroll
    for (int g = 0; g < 3; ++g) {
        #pragma unroll
        for (int ks = 0; ks < 4; ++ks) {
            const float* src = whh + (size_t)(g * 128 + j) * 128 + ks * 32 + q * 8;
            f16x8 b;
            #pragma unroll
            for (int e = 0; e < 8; ++e) b[e] = (f16)src[e];
            Bf[g][ks] = b;
        }
    }
    const float bh2 = bhh[j + 256];  // r,z biases folded into tab
    float hold[4];
    #pragma unroll
    for (int rr = 0; rr < 4; ++rr) hold[rr] = 0.f;
    __syncthreads();

    for (int t = 0; t < 128; ++t) {
        const int curb = t & 1, nxtb = curb ^ 1;
        const int tt = dir ? (127 - t) : t;

        int byt[4];
        #pragma unroll
        for (int rr = 0; rr < 4; ++rr) byt[rr] = flow_lds[q * 4 + rr][tt];
        float xr[4], xz[4], xn[4];
        #pragma unroll
        for (int rr = 0; rr < 4; ++rr) {
            const float* tb = tab + byt[rr] * 384 + j;
            xr[rr] = tb[0];
            xz[rr] = tb[128];
            xn[rr] = tb[256];
        }

        f16x8 Af[4];
        #pragma unroll
        for (int ks = 0; ks < 4; ++ks) {
            const int kb = ks * 32 + q * 8;
            const int idx = c * 128 + (kb ^ ((c & 7) << 3));
            Af[ks] = *reinterpret_cast<const f16x8*>(&hbuf[curb][idx]);
        }

        f32x4 a0 = {0.f, 0.f, 0.f, 0.f};
        f32x4 a1 = {0.f, 0.f, 0.f, 0.f};
        f32x4 a2 = {0.f, 0.f, 0.f, 0.f};
        #pragma unroll
        for (int ks = 0; ks < 4; ++ks) {
            a0 = __builtin_amdgcn_mfma_f32_16x16x32_f16(Af[ks], Bf[0][ks], a0, 0, 0, 0);
            a1 = __builtin_amdgcn_mfma_f32_16x16x32_f16(Af[ks], Bf[1][ks], a1, 0, 0, 0);
            a2 = __builtin_amdgcn_mfma_f32_16x16x32_f16(Af[ks], Bf[2][ks], a2, 0, 0, 0);
        }

        #pragma unroll
        for (int rr = 0; rr < 4; ++rr) {
            const float rg = fast_sigmoid(xr[rr] + a0[rr]);
            const float zg = fast_sigmoid(xz[rr] + a1[rr]);
            const float ng = fast_tanh(xn[rr] + rg * (a2[rr] + bh2));
            const float hn = fmaf(zg, hold[rr] - ng, ng);
            hold[rr] = hn;
            const int row = q * 4 + rr;
            hbuf[nxtb][row * 128 + (j ^ ((row & 7) << 3))] = (f16)hn;
        }
        __syncthreads();

        {
            const int row = tid >> 5;
            const int ho = (tid & 31) * 4;
            const int idx = row * 128 + (ho ^ ((row & 7) << 3));
            const uint2 v = *reinterpret_cast<const uint2*>(&hbuf[nxtb][idx]);
            *reinterpret_cast<uint2*>(
                &hout[((size_t)tt * 2048 + row0 + row) * 128 + ho]) = v;
        }
    }
}

// ---------------------------------------------------------------------------
// K3: byte attention scores + softmax fused.
// grid 2048 (128 positions = 2 complete (l,p) softmax groups), block 256.
__global__ __launch_bounds__(256, 1) void k_scores_attn(
    const __half* __restrict__ hF, const __half* __restrict__ hB,
    const float* __restrict__ w1,  // [128][256] row-major (= B[col][k])
    const float* __restrict__ b1, const float* __restrict__ w2,
    const float* __restrict__ b2, float* __restrict__ attn) {
    __shared__ f16 w1lds[128 * 256];  // 64 KB, swizzled col*256 + (k ^ ((col&7)<<3))
    __shared__ float sc[128];
    const int tid = threadIdx.x;
    for (int i = tid; i < 128 * 256; i += 256) {
        const int col = i >> 8, k = i & 255;
        w1lds[col * 256 + (k ^ ((col & 7) << 3))] = (f16)w1[i];
    }
    const int lane = tid & 63, w = tid >> 6;
    const int c = lane & 15, q = lane >> 4;
    const int pos0 = blockIdx.x * 128;

    // wave w handles position tiles pt = 2w, 2w+1 (16 positions each)
    f16x8 Af[2][8];
    #pragma unroll
    for (int pt = 0; pt < 2; ++pt) {
        const size_t pos = (size_t)pos0 + (w * 2 + pt) * 16 + c;
        const f16* hFp = (const f16*)(hF + pos * 128);
        const f16* hBp = (const f16*)(hB + pos * 128);
        #pragma unroll
        for (int ks = 0; ks < 4; ++ks)
            Af[pt][ks] = *reinterpret_cast<const f16x8*>(hFp + ks * 32 + q * 8);
        #pragma unroll
        for (int ks = 0; ks < 4; ++ks)
            Af[pt][4 + ks] = *reinterpret_cast<const f16x8*>(hBp + ks * 32 + q * 8);
    }

    float b1v[8], w2v[8];
    #pragma unroll
    for (int ct = 0; ct < 8; ++ct) {
        b1v[ct] = b1[ct * 16 + c];
        w2v[ct] = w2[ct * 16 + c];
    }
    const float b2v = b2[0];
    __syncthreads();

    float s[2][4] = {{0.f, 0.f, 0.f, 0.f}, {0.f, 0.f, 0.f, 0.f}};
    #pragma unroll
    for (int ct = 0; ct < 8; ++ct) {
        const int jj = ct * 16 + c;
        f16x8 Bfr[8];
        #pragma unroll
        for (int ks = 0; ks < 8; ++ks) {
            const int k = ks * 32 + q * 8;
            Bfr[ks] = *reinterpret_cast<const f16x8*>(
                &w1lds[jj * 256 + (k ^ ((jj & 7) << 3))]);
        }
        #pragma unroll
        for (int pt = 0; pt < 2; ++pt) {
            f32x4 acc = {0.f, 0.f, 0.f, 0.f};
            #pragma unroll
            for (int ks = 0; ks < 8; ++ks)
                acc = __builtin_amdgcn_mfma_f32_16x16x32_f16(Af[pt][ks], Bfr[ks],
                                                             acc, 0, 0, 0);
            #pragma unroll
            for (int rr = 0; rr < 4; ++rr)
                s[pt][rr] += w2v[ct] * fast_tanh(acc[rr] + b1v[ct]);
        }
    }
    #pragma unroll
    for (int pt = 0; pt < 2; ++pt) {
        #pragma unroll
        for (int rr = 0; rr < 4; ++rr) {
            float v = s[pt][rr];
            v += __shfl_xor(v, 1);
            v += __shfl_xor(v, 2);
            v += __shfl_xor(v, 4);
            v += __shfl_xor(v, 8);
            if (c == 0) sc[(w * 2 + pt) * 16 + q * 4 + rr] = v + b2v;
        }
    }
    __syncthreads();
    // softmax over b: groups of 64 (tid 0..63 = group 0 wave, 64..127 = group 1)
    if (tid < 128) {
        const float sv = sc[tid];
        float m = sv;
        for (int off = 32; off; off >>= 1) m = fmaxf(m, __shfl_xor(m, off));
        const float e = __expf(sv - m);
        float sum = e;
        for (int off = 32; off; off >>= 1) sum += __shfl_xor(sum, off);
        attn[pos0 + tid] = e / sum;
    }
}

// ---------------------------------------------------------------------------
// K3b: packet_emb[n,d] = sum_l attn[l,n] * h[l,n,d]. grid 512 (4 n each), block 256.
__global__ __launch_bounds__(256) void k_packet_emb(
    const __half* __restrict__ hF, const __half* __restrict__ hB,
    const float* __restrict__ attn, float* __restrict__ pe) {
    const int tid = threadIdx.x;
    const int g = tid >> 6;          // n group
    const int lane = tid & 63;
    const int n = blockIdx.x * 4 + g;
    const bool isF = lane < 32;
    const int chunk = lane & 31;     // 4 f16 per chunk
    const __half* __restrict__ hsrc = (isF ? hF : hB) + (size_t)n * 128 + chunk * 4;
    float acc0 = 0.f, acc1 = 0.f, acc2 = 0.f, acc3 = 0.f;
    #pragma unroll 4
    for (int l = 0; l < 128; ++l) {
        const float wv = attn[l * 2048 + n];
        const uint2 u = *reinterpret_cast<const uint2*>(hsrc + (size_t)l * 2048 * 128);
        const f16* hv = reinterpret_cast<const f16*>(&u);
        acc0 = fmaf(wv, (float)hv[0], acc0);
        acc1 = fmaf(wv, (float)hv[1], acc1);
        acc2 = fmaf(wv, (float)hv[2], acc2);
        acc3 = fmaf(wv, (float)hv[3], acc3);
    }
    float4 o = {acc0, acc1, acc2, acc3};
    *reinterpret_cast<float4*>(&pe[n * 256 + (isF ? 0 : 128) + chunk * 4]) = o;
}

// ---------------------------------------------------------------------------
// K4pre: xg2[p,n,g] = b_ih[g] (+b_hh r/z) + sum_d pe[p,n,d]*w_ih[g,d].
// grid (256,2), block 384.
__global__ __launch_bounds__(384) void k_pkt_xg(
    const float* __restrict__ pe, const float* __restrict__ wihTF,
    const float* __restrict__ bihF, const float* __restrict__ bhhF,
    const float* __restrict__ wihTB, const float* __restrict__ bihB,
    const float* __restrict__ bhhB, float* __restrict__ xgF,
    float* __restrict__ xgB) {
    const int dir = blockIdx.y;
    const float* __restrict__ wihT = dir ? wihTB : wihTF;
    const float* __restrict__ bih = dir ? bihB : bihF;
    const float* __restrict__ bhh = dir ? bhhB : bhhF;
    float* __restrict__ xg = dir ? xgB : xgF;
    const int rbase = blockIdx.x * 8;
    __shared__ float xrow[8][256];
    for (int i = threadIdx.x; i < 8 * 256; i += 384)
        xrow[i >> 8][i & 255] = pe[rbase * 256 + i];
    __syncthreads();
    const int g = threadIdx.x;
    float acc[8];
    const float bias = bih[g] + (g < 256 ? bhh[g] : 0.0f);
    #pragma unroll
    for (int r = 0; r < 8; ++r) acc[r] = bias;
    for (int d = 0; d < 256; ++d) {
        const float w = wihT[d * 384 + g];
        #pragma unroll
        for (int r = 0; r < 8; ++r) acc[r] = fmaf(w, xrow[r][d], acc[r]);
    }
    #pragma unroll
    for (int r = 0; r < 8; ++r) xg[(rbase + r) * 384 + g] = acc[r];
}

// ---------------------------------------------------------------------------
// K4: packet BiGRU via MFMA f16. grid 8 (dir=bx&1, chunk=bx>>1: 16 rows),
// block 512 (8 waves), 32 steps. Same structure as k_byte_gru.
__global__ __launch_bounds__(512, 1) void k_pkt_gru(
    const float* __restrict__ xgF, const float* __restrict__ xgB,
    const float* __restrict__ whhF, const float* __restrict__ whhB,
    const float* __restrict__ bhhF, const float* __restrict__ bhhB,
    float* __restrict__ h2F, float* __restrict__ h2B) {
    const int dir = blockIdx.x & 1;
    const int chunk = blockIdx.x >> 1;  // 0..3
    const int row0 = chunk * 16;
    const int tid = threadIdx.x;
    const int wid = tid >> 6;
    const int lane = tid & 63;
    const int c = lane & 15;
    const int q = lane >> 4;
    const int j = wid * 16 + c;

    const float* __restrict__ xg = dir ? xgB : xgF;
    const float* __restrict__ whh = dir ? whhB : whhF;
    const float* __restrict__ bhh = dir ? bhhB : bhhF;
    float* __restrict__ hout = dir ? h2B : h2F;

    __shared__ f16 hbuf[2][16 * 128];  // swizzled: row*128 + (k ^ ((row&7)<<3))

    for (int i = tid; i < 16 * 128; i += 512) hbuf[0][i] = (f16)0.f;

    f16x8 Bf[3][4];
    #pragma unroll
    for (int g = 0; g < 3; ++g) {
        #pragma unroll
        for (int ks = 0; ks < 4; ++ks) {
            const float* src = whh + (size_t)(g * 128 + j) * 128 + ks * 32 + q * 8;
            f16x8 b;
            #pragma unroll
            for (int e = 0; e < 8; ++e) b[e] = (f16)src[e];
            Bf[g][ks] = b;
        }
    }
    const float bh2 = bhh[j + 256];  // r,z biases folded into xg
    float hold[4];
    #pragma unroll
    for (int rr = 0; rr < 4; ++rr) hold[rr] = 0.f;
    __syncthreads();

    for (int t = 0; t < 32; ++t) {
        const int curb = t & 1, nxtb = curb ^ 1;
        const int tt = dir ? (31 - t) : t;

        // xg loads (independent of h -> overlap with ds_read+MFMA latency)
        float xr[4], xz[4], xn[4];
        #pragma unroll
        for (int rr = 0; rr < 4; ++rr) {
            const float* xp = xg + ((size_t)tt * 64 + row0 + q * 4 + rr) * 384 + j;
            xr[rr] = xp[0];
            xz[rr] = xp[128];
            xn[rr] = xp[256];
        }

        f16x8 Af[4];
        #pragma unroll
        for (int ks = 0; ks < 4; ++ks) {
            const int kb = ks * 32 + q * 8;
            const int idx = c * 128 + (kb ^ ((c & 7) << 3));
            Af[ks] = *reinterpret_cast<const f16x8*>(&hbuf[curb][idx]);
        }

        f32x4 a0 = {0.f, 0.f, 0.f, 0.f};
        f32x4 a1 = {0.f, 0.f, 0.f, 0.f};
        f32x4 a2 = {0.f, 0.f, 0.f, 0.f};
        #pragma unroll
        for (int ks = 0; ks < 4; ++ks) {
            a0 = __builtin_amdgcn_mfma_f32_16x16x32_f16(Af[ks], Bf[0][ks], a0, 0, 0, 0);
            a1 = __builtin_amdgcn_mfma_f32_16x16x32_f16(Af[ks], Bf[1][ks], a1, 0, 0, 0);
            a2 = __builtin_amdgcn_mfma_f32_16x16x32_f16(Af[ks], Bf[2][ks], a2, 0, 0, 0);
        }

        #pragma unroll
        for (int rr = 0; rr < 4; ++rr) {
            const float rg = fast_sigmoid(xr[rr] + a0[rr]);
            const float zg = fast_sigmoid(xz[rr] + a1[rr]);
            const float ng = fast_tanh(xn[rr] + rg * (a2[rr] + bh2));
            const float hn = fmaf(zg, hold[rr] - ng, ng);
            hold[rr] = hn;
            const int row = q * 4 + rr;
            hbuf[nxtb][row * 128 + (j ^ ((row & 7) << 3))] = (f16)hn;
            hout[((size_t)tt * 64 + row0 + row) * 128 + j] = hn;
        }
        __syncthreads();
    }
}

// ---------------------------------------------------------------------------
// K5a: packet attention scores. grid 2048 (n), block 128.
__global__ __launch_bounds__(128) void k_scores2(
    const float* __restrict__ h2F, const float* __restrict__ h2B,
    const float* __restrict__ paw1,  // [128][256] row-major
    const float* __restrict__ pab1, const float* __restrict__ paw2,
    const float* __restrict__ pab2, float* __restrict__ scores2) {
    const int n = blockIdx.x;
    const int tid = threadIdx.x;  // 128
    __shared__ float x[256];
    __shared__ float red[2];
    x[tid] = h2F[n * 128 + tid];
    x[tid + 128] = h2B[n * 128 + tid];
    __syncthreads();
    float acc = pab1[tid];
    const float* wr = paw1 + tid * 256;
    #pragma unroll 8
    for (int d = 0; d < 256; ++d) acc = fmaf(wr[d], x[d], acc);
    float s = paw2[tid] * fast_tanh(acc);
    s += __shfl_xor(s, 1);
    s += __shfl_xor(s, 2);
    s += __shfl_xor(s, 4);
    s += __shfl_xor(s, 8);
    s += __shfl_xor(s, 16);
    s += __shfl_xor(s, 32);
    if ((tid & 63) == 0) red[tid >> 6] = s;
    __syncthreads();
    if (tid == 0) scores2[n] = red[0] + red[1] + pab2[0];
}

// ---------------------------------------------------------------------------
// K5b: softmax over b + weighted sum + final FC. grid 32 (p), block 256.
__global__ __launch_bounds__(256) void k_final3(
    const float* __restrict__ h2F, const float* __restrict__ h2B,
    const float* __restrict__ scores2, const float* __restrict__ wf,
    const float* __restrict__ bfv, float* __restrict__ outp) {
    const int p = blockIdx.x;
    const int tid = threadIdx.x;
    __shared__ float sc[64];
    __shared__ float femb[256];
    __shared__ float red[64];

    if (tid < 64) {
        const float s = scores2[p * 64 + tid];
        float m = s;
        for (int off = 32; off; off >>= 1) m = fmaxf(m, __shfl_xor(m, off));
        const float e = __expf(s - m);
        float sum = e;
        for (int off = 32; off; off >>= 1) sum += __shfl_xor(sum, off);
        sc[tid] = e / sum;
    }
    __syncthreads();

    {
        const float* __restrict__ hsrc = (tid < 128) ? h2F : h2B;
        const int d = tid & 127;
        float acc = 0.f;
        for (int b = 0; b < 64; ++b)
            acc = fmaf(sc[b], hsrc[(p * 64 + b) * 128 + d], acc);
        femb[tid] = acc;
    }
    __syncthreads();

    const float fv = femb[tid];
    #pragma unroll
    for (int c = 0; c < 10; ++c) {
        float s = fv * wf[c * 256 + tid];
        s += __shfl_xor(s, 1);
        s += __shfl_xor(s, 2);
        s += __shfl_xor(s, 4);
        s += __shfl_xor(s, 8);
        s += __shfl_xor(s, 16);
        s += __shfl_xor(s, 32);
        if ((tid & 63) == 0) red[(c << 2) | (tid >> 6)] = s;
        __syncthreads();
        if (tid == 0)
            outp[p * 10 + c] = bfv[c] + red[c << 2] + red[(c << 2) | 1] +
                               red[(c << 2) | 2] + red[(c << 2) | 3];
        __syncthreads();
    }
}

// ---------------------------------------------------------------------------
extern "C" void kernel_launch(void* const* d_in, const int* in_sizes, int n_in,
                              void* d_out, int out_size, void* d_ws,
                              size_t ws_size, hipStream_t stream) {
    const int* flow = (const int*)d_in[0];
    const float* emb = (const float*)d_in[1];
    const float* byte_wih_f = (const float*)d_in[2];
    const float* byte_whh_f = (const float*)d_in[3];
    const float* byte_bih_f = (const float*)d_in[4];
    const float* byte_bhh_f = (const float*)d_in[5];
    const float* byte_wih_b = (const float*)d_in[6];
    const float* byte_whh_b = (const float*)d_in[7];
    const float* byte_bih_b = (const float*)d_in[8];
    const float* byte_bhh_b = (const float*)d_in[9];
    const float* pkt_wih_f = (const float*)d_in[10];
    const float* pkt_whh_f = (const float*)d_in[11];
    const float* pkt_bih_f = (const float*)d_in[12];
    const float* pkt_bhh_f = (const float*)d_in[13];
    const float* pkt_wih_b = (const float*)d_in[14];
    const float* pkt_whh_b = (const float*)d_in[15];
    const float* pkt_bih_b = (const float*)d_in[16];
    const float* pkt_bhh_b = (const float*)d_in[17];
    const float* ba_w1 = (const float*)d_in[18];
    const float* ba_b1 = (const float*)d_in[19];
    const float* ba_w2 = (const float*)d_in[20];
    const float* ba_b2 = (const float*)d_in[21];
    const float* pa_w1 = (const float*)d_in[22];
    const float* pa_b1 = (const float*)d_in[23];
    const float* pa_w2 = (const float*)d_in[24];
    const float* pa_b2 = (const float*)d_in[25];
    const float* wf = (const float*)d_in[26];
    const float* bf = (const float*)d_in[27];

    char* base = (char*)d_ws;
    size_t off = 0;
    auto allocf = [&](size_t nf) -> float* {
        float* p = (float*)(base + off);
        off += nf * sizeof(float);
        return p;
    };
    auto alloch = [&](size_t nh) -> __half* {
        off = (off + 255) & ~(size_t)255;
        __half* p = (__half*)(base + off);
        off += nh * sizeof(__half);
        return p;
    };
    float* tabF = allocf(256 * 384);
    float* tabB = allocf(256 * 384);
    float* wihTpF = allocf(256 * 384);
    float* wihTpB = allocf(256 * 384);
    float* attn = allocf(262144);
    float* pe = allocf(2048 * 256);
    float* xgF = allocf(32 * 64 * 384);
    float* xgB = allocf(32 * 64 * 384);
    float* h2F = allocf(32 * 64 * 128);
    float* h2B = allocf(32 * 64 * 128);
    float* scores2 = allocf(2048);
    __half* hF = alloch((size_t)128 * 2048 * 128);
    __half* hB = alloch((size_t)128 * 2048 * 128);
    if (off > ws_size) return;  // diagnostic: leaves d_out poisoned
    (void)in_sizes; (void)n_in; (void)out_size;

    k_tables<<<512, 384, 0, stream>>>(emb, byte_wih_f, byte_bih_f, byte_bhh_f,
                                      byte_wih_b, byte_bih_b, byte_bhh_b, tabF,
                                      tabB);

    TransArgs ta;
    ta.src[0] = pkt_wih_f; ta.dst[0] = wihTpF; ta.R[0] = 384; ta.C[0] = 256;
    ta.src[1] = pkt_wih_b; ta.dst[1] = wihTpB; ta.R[1] = 384; ta.C[1] = 256;
    k_transpose<<<dim3(96, 2), 256, 0, stream>>>(ta);

    k_byte_gru<<<256, 512, 0, stream>>>(flow, tabF, tabB, byte_whh_f,
                                        byte_whh_b, byte_bhh_f, byte_bhh_b, hF,
                                        hB);

    k_scores_attn<<<2048, 256, 0, stream>>>(hF, hB, ba_w1, ba_b1, ba_w2, ba_b2,
                                            attn);
    k_packet_emb<<<512, 256, 0, stream>>>(hF, hB, attn, pe);

    k_pkt_xg<<<dim3(256, 2), 384, 0, stream>>>(pe, wihTpF, pkt_bih_f,
                                               pkt_bhh_f, wihTpB, pkt_bih_b,
                                               pkt_bhh_b, xgF, xgB);
    k_pkt_gru<<<8, 512, 0, stream>>>(xgF, xgB, pkt_whh_f, pkt_whh_b,
                                     pkt_bhh_f, pkt_bhh_b, h2F, h2B);
    k_scores2<<<2048, 128, 0, stream>>>(h2F, h2B, pa_w1, pa_b1, pa_w2, pa_b2,
                                        scores2);
    k_final3<<<32, 256, 0, stream>>>(h2F, h2B, scores2, wf, bf, (float*)d_out);
}